// Round 16
// baseline (445.970 us; speedup 1.0000x reference)
//
#include <hip/hip_runtime.h>
#include <cstdint>
#include <cstddef>

// ============================================================================
// CHMLearner forward. R16: fast4d v6 (y-split x2 -> 2048 blocks x 128 thr,
// double occupancy; rowmax -> 2 partials folded into k_mutual);
// colmax_p 512 blocks. Rest identical to R15.
// ============================================================================

#define DEVFN __device__ __forceinline__

typedef __attribute__((ext_vector_type(8))) short short8v;
typedef __attribute__((ext_vector_type(4))) float f32x4;
typedef unsigned int u32;

DEVFN void gl_lds16(const void* g, void* l){
  __builtin_amdgcn_global_load_lds(
      (const __attribute__((address_space(1))) u32*)g,
      (__attribute__((address_space(3))) u32*)l, 16, 0, 0);
}

// workspace layout (float units). Total ~72.5 MB
constexpr size_t OFF_WB    = 0;           // bf16 packed conv weights
constexpr size_t OFF_P8    = 3538944;     // bf16 padded ch-last features
constexpr size_t OFF_P16   = 3948544;
constexpr size_t OFF_P32   = 5275648;
constexpr size_t OFF_SF8   = 10010624;    // conv outputs f32 [b][256][S*S]
constexpr size_t OFF_TF8   = 10076160;
constexpr size_t OFF_SF16  = 10141696;
constexpr size_t OFF_TF16  = 10403840;
constexpr size_t OFF_SF32  = 10665984;
constexpr size_t OFF_TF32  = 11714560;
constexpr size_t OFF_INVS  = 12763136;
constexpr size_t OFF_INVT  = 12768512;
constexpr size_t OFF_TMAX  = 12777984;
constexpr size_t OFF_CORR6 = 12782080;    // [4][9][16^4] f32
constexpr size_t OFF_CMAXP = OFF_CORR6 + 2359296 + 128;   // 131072 colmax partials
constexpr size_t OFF_WA    = OFF_CMAXP + 131072;          // 192,000 bf16
constexpr size_t OFF_PARTK = OFF_WA + 96128;              // 2,752,512 conv K-partials
constexpr size_t OFF_SMAXP = OFF_PARTK + 2752512;         // [2][4][1024] rowmax partials
constexpr size_t WS_FLOATS = OFF_SMAXP + 8192;

// aliases into dead regions:
__device__ constexpr size_t PAIR_OFF[9] = {   // raw per-pair corr [4][ss^2][ts^2]
  OFF_WB + 0,       OFF_WB + 16384,   OFF_WB + 81920,
  OFF_WB + 344064,  OFF_WB + 409600,  OFF_WB + 671744,
  OFF_WB + 1720320, OFF_WB + 1982464, OFF_WB + 3031040 };
constexpr size_t OFF_CL    = 0;            // bf16 [4][256][20][21][24]
constexpr size_t OFF_MAXED = 9437184;      // [4][16^4] f32
constexpr size_t OFF_INT32 = 262144;       // [4][32^4] f32 (CL dead by interp32)
constexpr size_t OFF_FB    = OFF_PARTK;    // bf16 [10752 rows][256 ch] (PARTK dead)

__device__ constexpr int SSARR[3] = {8, 16, 32};
__device__ constexpr int PAIR_START[9] = {0,4,20,84,100,164,420,484,740}; // 1764

DEVFN unsigned short f2bf(float f){
  unsigned int u = __float_as_uint(f);
  return (unsigned short)((u + 0x7fffu + ((u >> 16) & 1u)) >> 16);
}
DEVFN float bf2f(unsigned short u){
  return __uint_as_float(((unsigned int)u) << 16);
}

// ---------------------------------------------------------------------------
// 1) wpack v2: coalesced via LDS transpose (R13)
__global__ __launch_bounds__(256) void k_wpack(const float* __restrict__ w0,
                                               const float* __restrict__ w1,
                                               const float* __restrict__ w2,
                                               float* __restrict__ wsf){
  int bx = blockIdx.x;
  int scale = bx >> 8, cg = (bx >> 4) & 15, ig = bx & 15;
  const float* w = (scale==0) ? w0 : (scale==1 ? w1 : w2);
  const int t = threadIdx.x;
  __shared__ float sW[16*580];
  const float* src = w + (size_t)cg*16*9216 + (size_t)ig*576;
  for (int i=t; i<9216; i+=256){
    int co = i/576, r = i%576;
    sW[co*580 + r] = src[(size_t)co*9216 + r];
  }
  __syncthreads();
  unsigned short* ob = (unsigned short*)(wsf + OFF_WB) + (size_t)scale*2359296;
  for (int f=t; f<1152; f+=256){
    int tap = f/128, rem = f%128, kcl = rem>>6, l = rem&63;
    int kc = ig*2 + kcl;
    int co = l & 15;
    int ciL = kcl*32 + ((l>>4)&3)*8;
    unsigned short* o = ob + ((size_t)tap*32768 + (size_t)kc*1024 + (size_t)cg*64 + l)*8;
    #pragma unroll
    for (int i=0;i<8;i++)
      o[i] = f2bf(sW[co*580 + (ciL+i)*9 + tap]);
  }
}

// 1b) pack chm6d weights into MFMA A-fragment order
__global__ void k_wa(const float* __restrict__ k6, float* __restrict__ wsf){
  int gid = blockIdx.x*256 + threadIdx.x;        // 24,000
  if (gid >= 24000) return;
  int tap = gid / 192, rem = gid % 192;
  int kc = rem / 64, l = rem % 64;
  int d = tap % 5, ac = tap / 5, a = ac / 5, c = ac % 5;
  int so = l & 15, k8 = (l >> 4) * 8;
  unsigned short* o = (unsigned short*)(wsf + OFF_WA) + (size_t)gid*8;
  #pragma unroll
  for (int i=0;i<8;i++){
    int kg = kc*32 + k8 + i;
    int e = kg >> 4, pr = kg & 15;
    float v = 0.f;
    if (so < 9 && pr < 9 && e < 5){
      int pi = pr/3, pj = pr%3, sio = so/3, sjo = so%3;
      int ki = pi - sio + 1, kj = pj - sjo + 1;
      if (ki>=0 && ki<=2 && kj>=0 && kj<=2)
        v = k6[(((((ki*3+kj)*5 + a)*5 + c)*5 + d)*5) + e];
    }
    o[i] = f2bf(v);
  }
}

// ---------------------------------------------------------------------------
// 2) inpack: stage 16 channels' 16x16 planes in LDS; emit all 3 scales
__global__ __launch_bounds__(256) void k_inpack(const float* __restrict__ src,
                                                const float* __restrict__ trg,
                                                float* __restrict__ wsf){
  int bt = blockIdx.x >> 6, cg = blockIdx.x & 63;
  int chbase = cg*16;
  int t = threadIdx.x;
  __shared__ float sIn[16][257];
  const float* gin = ((bt>=4)? trg : src) + ((size_t)(bt&3)*1024 + chbase)*256;
  #pragma unroll
  for (int i=0;i<16;i++){
    int idx = t + i*256; int ch = idx>>8, pos = idx&255;
    sIn[ch][pos] = gin[(size_t)ch*256 + pos];
  }
  __syncthreads();
  int ch = t & 15, pw = t >> 4;
  #pragma unroll 1
  for (int s=0; s<3; s++){
    int S = SSARR[s], Sp = S+2, Sp2 = Sp*Sp;
    size_t poff = (s==0)?OFF_P8 : (s==1)?OFF_P16 : OFF_P32;
    unsigned short* o = (unsigned short*)(wsf + poff) + (size_t)bt*Sp2*1024 + chbase + ch;
    float rs = 15.f/(float)(S-1);
    for (int i = pw; i < Sp2; i += 16){
      int py = i / Sp, px = i % Sp;
      float v = 0.f;
      if (py>0 && py<Sp-1 && px>0 && px<Sp-1){
        float cy = (float)(py-1)*rs, cx = (float)(px-1)*rs;
        int y0 = (int)cy; if (y0>15) y0=15; int y1 = (y0+1<16)?y0+1:15; float fy = cy-(float)y0;
        int x0 = (int)cx; if (x0>15) x0=15; int x1 = (x0+1<16)?x0+1:15; float fx = cx-(float)x0;
        v = (1.f-fy)*((1.f-fx)*sIn[ch][y0*16+x0] + fx*sIn[ch][y0*16+x1])
          +       fy*((1.f-fx)*sIn[ch][y1*16+x0] + fx*sIn[ch][y1*16+x1]);
      }
      o[(size_t)i*1024] = f2bf(v);
    }
  }
}

// ---------------------------------------------------------------------------
// 3) conv3x3 bf16 MFMA GEMM, K-split x2 (R12)
__global__ __launch_bounds__(256) void k_conv_mfma(float* __restrict__ wsf){
  int bs = (blockIdx.x & 7)*84 + (blockIdx.x >> 3);   // bijective, 672 blocks
  const int ks = bs & 1;
  int bx = bs >> 1;
  int scale, bt, cot, post, S, lgS;
  if (bx < 256)      { scale=2; S=32; lgS=5; bt=bx>>5; cot=(bx>>4)&1; post=bx&15; }
  else if (bx < 320) { int r=bx-256; scale=1; S=16; lgS=4; bt=r>>3; cot=(r>>2)&1; post=r&3; }
  else               { int r=bx-320; scale=0; S=8;  lgS=3; bt=r>>1; cot=r&1; post=0; }
  const int Sp = S+2, N = S*S;
  const unsigned short* WbS = (const unsigned short*)(wsf + OFF_WB) + (size_t)scale*2359296;
  size_t poff = scale==0?OFF_P8: scale==1?OFF_P16:OFF_P32;
  const unsigned short* Pb = (const unsigned short*)(wsf + poff) + (size_t)bt*Sp*Sp*1024;
  size_t obase = (scale==2) ? (bt>=4?OFF_TF32:OFF_SF32)
               : (scale==1) ? (bt>=4?OFF_TF16:OFF_SF16)
                            : (bt>=4?OFF_TF8 :OFF_SF8);
  if (ks) obase += OFF_PARTK - OFF_SF8;
  float* outp = wsf + obase + (size_t)(bt&3)*256*N;

  const int t = threadIdx.x, l = t&63, w = t>>6, wm = w&1, wn = w>>1;
  const int nc_base = cot*8;
  const int pos0 = post*64;
  const int it0 = ks*72, it1 = it0 + 72;

  __shared__ __align__(16) unsigned short Ab[2][8192];   // 32 KB
  __shared__ __align__(16) unsigned short Bb[2][4096];   // 16 KB

  f32x4 acc[4][2];
  #pragma unroll
  for (int i=0;i<4;i++)
    #pragma unroll
    for (int j=0;j<2;j++) acc[i][j] = (f32x4){0.f,0.f,0.f,0.f};

  auto STAGE = [&](int buf, int it){
    int tap = it>>4, kq = it&15;
    int dy = tap/3, dx = tap - dy*3;
    #pragma unroll
    for (int j=0;j<4;++j){
      int c = w + j*4;
      int kc = c>>3, nc = c&7;
      const unsigned short* src =
        WbS + ((((size_t)tap*32 + kq*2 + kc)*16 + nc_base + nc)*64 + l)*8;
      gl_lds16(src, &Ab[buf][c*512]);
    }
    #pragma unroll
    for (int j=0;j<2;++j){
      int c = w + j*4;
      int kc = c>>2, np = c&3;
      int pos = pos0 + np*16 + (l&15);
      int y = pos>>lgS, x = pos&(S-1);
      int row = (y+dy)*Sp + (x+dx);
      int ci = kq*64 + kc*32 + ((l>>4)<<3);
      gl_lds16(Pb + (size_t)row*1024 + ci, &Bb[buf][c*512]);
    }
  };

  STAGE(0, it0);
  __syncthreads();
  int buf = 0;
  #pragma unroll 1
  for (int it=it0; it<it1; ++it){
    if (it+1 < it1) STAGE(buf^1, it+1);
    #pragma unroll
    for (int kc=0; kc<2; ++kc){
      short8v a0 = *(const short8v*)&Ab[buf][((kc*8 + wm*4 + 0)*64 + l)*8];
      short8v a1 = *(const short8v*)&Ab[buf][((kc*8 + wm*4 + 1)*64 + l)*8];
      short8v a2 = *(const short8v*)&Ab[buf][((kc*8 + wm*4 + 2)*64 + l)*8];
      short8v a3 = *(const short8v*)&Ab[buf][((kc*8 + wm*4 + 3)*64 + l)*8];
      short8v b0 = *(const short8v*)&Bb[buf][((kc*4 + wn*2 + 0)*64 + l)*8];
      short8v b1 = *(const short8v*)&Bb[buf][((kc*4 + wn*2 + 1)*64 + l)*8];
      acc[0][0] = __builtin_amdgcn_mfma_f32_16x16x32_bf16(a0, b0, acc[0][0], 0,0,0);
      acc[1][0] = __builtin_amdgcn_mfma_f32_16x16x32_bf16(a1, b0, acc[1][0], 0,0,0);
      acc[2][0] = __builtin_amdgcn_mfma_f32_16x16x32_bf16(a2, b0, acc[2][0], 0,0,0);
      acc[3][0] = __builtin_amdgcn_mfma_f32_16x16x32_bf16(a3, b0, acc[3][0], 0,0,0);
      acc[0][1] = __builtin_amdgcn_mfma_f32_16x16x32_bf16(a0, b1, acc[0][1], 0,0,0);
      acc[1][1] = __builtin_amdgcn_mfma_f32_16x16x32_bf16(a1, b1, acc[1][1], 0,0,0);
      acc[2][1] = __builtin_amdgcn_mfma_f32_16x16x32_bf16(a2, b1, acc[2][1], 0,0,0);
      acc[3][1] = __builtin_amdgcn_mfma_f32_16x16x32_bf16(a3, b1, acc[3][1], 0,0,0);
    }
    __syncthreads();
    buf ^= 1;
  }

  const int r0 = (l>>4)*4, cl = l&15;
  float* ob = outp + (size_t)(cot*128 + wm*64)*N + pos0 + wn*32 + cl;
  #pragma unroll
  for (int mf=0; mf<4; ++mf)
    #pragma unroll
    for (int nf=0; nf<2; ++nf){
      float* op = ob + (size_t)(mf*16 + r0)*N + nf*16;
      #pragma unroll
      for (int i=0;i<4;++i) op[(size_t)i*N] = acc[mf][nf][i];
    }
}

// 3b) combine conv K-partials: outputs += PARTK
__global__ void k_combine(float* __restrict__ ws){
  int i = blockIdx.x*256 + threadIdx.x;          // 2,752,512 exact
  ws[OFF_SF8 + i] += ws[OFF_PARTK + i];
}

// ---------------------------------------------------------------------------
// 3c) fbpack: transpose conv outputs f32 [ch][P] -> FB bf16 [row=pos][256ch]
__global__ __launch_bounds__(256) void k_fbpack(float* __restrict__ ws){
  int bx = blockIdx.x;
  int tsr = bx/84, r = bx%84;
  int s, b, chunk;
  if (r < 4)       { s=0; b=r;        chunk=0; }
  else if (r < 20) { s=1; int q=r-4;  b=q>>2; chunk=q&3; }
  else             { s=2; int q=r-20; b=q>>4; chunk=q&15; }
  int P = SSARR[s]*SSARR[s];
  size_t fbase = (s==0)? (tsr?OFF_TF8 :OFF_SF8)
               : (s==1)? (tsr?OFF_TF16:OFF_SF16)
                       : (tsr?OFF_TF32:OFF_SF32);
  const float* src = ws + fbase + (size_t)b*256*P;
  int pos0 = chunk*64;
  const int t = threadIdx.x;
  __shared__ float tile[64][260];
  for (int i=0;i<64;i++){
    int idx = t + i*256; int ch = idx>>6, pl = idx&63;
    tile[pl][ch] = src[(size_t)ch*P + pos0 + pl];
  }
  __syncthreads();
  int rowbase = tsr*5376 + (s==0?0: s==1?256:1280) + b*P + pos0;
  unsigned short* FB = (unsigned short*)(ws + OFF_FB);
  for (int i=0;i<64;i++){
    int idx = t + i*256; int pl = idx>>8, ch = idx&255;
    FB[(size_t)(rowbase+pl)*256 + ch] = f2bf(tile[pl][ch]);
  }
}

// 4) invnorm v2: per FB row 1/||.||
__global__ void k_invnorm(float* __restrict__ ws){
  int id = blockIdx.x*256 + threadIdx.x;
  if (id >= 10752) return;
  const unsigned short* fb = (const unsigned short*)(ws + OFF_FB) + (size_t)id*256;
  float s = 0.f;
  #pragma unroll 4
  for (int i=0;i<32;i++){
    short8v v = *(const short8v*)(fb + i*8);
    #pragma unroll
    for (int j=0;j<8;j++){
      float f = bf2f(((unsigned short*)&v)[j]);
      s = fmaf(f, f, s);
    }
  }
  int tsr = id/5376, r = id%5376;
  ws[(tsr ? OFF_INVT : OFF_INVS) + r] = 1.f/sqrtf(s);
}

// ---------------------------------------------------------------------------
// 5) corr v2: bf16 MFMA GEMM, 64x64 tiles, K=256, operands direct from FB
__global__ __launch_bounds__(256) void k_corr(float* __restrict__ ws){
  int bx = blockIdx.x;
  int p = (bx>=4)+(bx>=20)+(bx>=84)+(bx>=100)+(bx>=164)+(bx>=420)+(bx>=484)+(bx>=740);
  int si = p/3, ti = p%3;
  int M = SSARR[si]*SSARR[si], N = SSARR[ti]*SSARR[ti];
  int ntN = N >> 6;
  int rem = bx - PAIR_START[p];
  int b = rem & 3; rem >>= 2;
  int nt = rem % ntN, mt = rem / ntN;
  int m0 = mt*64, n0 = nt*64;
  const unsigned short* FB = (const unsigned short*)(ws + OFF_FB);
  const unsigned short* Ap = FB + (size_t)((si==0?0: si==1?256:1280) + b*M + m0)*256;
  const unsigned short* Bp = FB + (size_t)(5376 + (ti==0?0: ti==1?256:1280) + b*N + n0)*256;
  const int t = threadIdx.x, l = t&63, w = t>>6, wm = w&1, wn = w>>1;
  const int mrow = wm*32 + (l&15), ncol = wn*32 + (l&15);
  f32x4 acc[2][2];
  #pragma unroll
  for (int i=0;i<2;i++)
    #pragma unroll
    for (int j=0;j<2;j++) acc[i][j] = (f32x4){0.f,0.f,0.f,0.f};
  #pragma unroll
  for (int ksp=0; ksp<8; ++ksp){
    const int ko = ksp*32 + ((l>>4)&3)*8;
    short8v a0 = *(const short8v*)(Ap + (size_t) mrow     *256 + ko);
    short8v a1 = *(const short8v*)(Ap + (size_t)(mrow+16) *256 + ko);
    short8v b0 = *(const short8v*)(Bp + (size_t) ncol     *256 + ko);
    short8v b1 = *(const short8v*)(Bp + (size_t)(ncol+16) *256 + ko);
    acc[0][0] = __builtin_amdgcn_mfma_f32_16x16x32_bf16(a0, b0, acc[0][0], 0,0,0);
    acc[1][0] = __builtin_amdgcn_mfma_f32_16x16x32_bf16(a1, b0, acc[1][0], 0,0,0);
    acc[0][1] = __builtin_amdgcn_mfma_f32_16x16x32_bf16(a0, b1, acc[0][1], 0,0,0);
    acc[1][1] = __builtin_amdgcn_mfma_f32_16x16x32_bf16(a1, b1, acc[1][1], 0,0,0);
  }
  const float* iS = ws + OFF_INVS + (si==0?0: si==1?256:1280) + (size_t)b*M;
  const float* iT = ws + OFF_INVT + (ti==0?0: ti==1?256:1280) + (size_t)b*N;
  float* C = ws + PAIR_OFF[p] + (size_t)b*M*N;
  const int r0 = (l>>4)*4, cl = l&15;
  #pragma unroll
  for (int mf=0; mf<2; ++mf)
    #pragma unroll
    for (int nf=0; nf<2; ++nf)
      #pragma unroll
      for (int i=0;i<4;++i){
        int m = m0 + wm*32 + mf*16 + r0 + i;
        int n = n0 + wn*32 + nf*16 + cl;
        C[(size_t)m*N + n] = acc[mf][nf][i]*iS[m]*iT[n];
      }
}

// ---------------------------------------------------------------------------
DEVFN void cw_coord(int i, int n, int OH, int& i0, int& i1, float& f){
  float c = (float)(i*(n-1))/(float)(OH-1);
  int a = (int)c; if (a > n-1) a = n-1;
  i0 = a; i1 = (a+1 < n) ? a+1 : n-1; f = c - (float)a;
}

// 6) interp_pairs v2: block = (p,b,oy,ox); stage 4 corner (y,x) planes in LDS
__global__ __launch_bounds__(256) void k_interp_pairs(float* __restrict__ ws){
  int bx = blockIdx.x;
  int p = bx >> 10;
  int bl = bx & 1023;                    // [b:2][oy:4][ox:4]
  int b = bl >> 8, oy = (bl >> 4) & 15, ox = bl & 15;
  int si = p/3, ti = p%3;
  int h1 = SSARR[si], t1 = SSARR[ti], t12 = t1*t1;
  int y0,y1,x0,x1; float fy,fx;
  cw_coord(oy,h1,16,y0,y1,fy); cw_coord(ox,h1,16,x0,x1,fx);
  const float* in = ws + PAIR_OFF[p] + (size_t)b*h1*h1*t12;
  __shared__ float sPl[4][1024];
  const int t = threadIdx.x;
  {
    const float* pl0 = in + (size_t)(y0*h1+x0)*t12;
    const float* pl1 = in + (size_t)(y0*h1+x1)*t12;
    const float* pl2 = in + (size_t)(y1*h1+x0)*t12;
    const float* pl3 = in + (size_t)(y1*h1+x1)*t12;
    for (int i=t; i<t12; i+=256){
      sPl[0][i] = pl0[i]; sPl[1][i] = pl1[i];
      sPl[2][i] = pl2[i]; sPl[3][i] = pl3[i];
    }
  }
  __syncthreads();
  int px = t & 15, py = t >> 4;
  int u0,u1,v0,v1; float fu,fv;
  cw_coord(py,t1,16,u0,u1,fu); cw_coord(px,t1,16,v0,v1,fv);
  float wY[2]={1.f-fy,fy}, wX[2]={1.f-fx,fx};
  float wU[2]={1.f-fu,fu}, wV[2]={1.f-fv,fv};
  int us[2]={u0,u1}, vs[2]={v0,v1};
  float s = 0.f;
  #pragma unroll
  for (int qa=0; qa<2; qa++)
    #pragma unroll
    for (int qc=0; qc<2; qc++){
      float wyx = wY[qa]*wX[qc];
      const float* base = sPl[qa*2+qc];
      #pragma unroll
      for (int qu=0; qu<2; qu++)
        #pragma unroll
        for (int qv=0; qv<2; qv++)
          s += wyx*wU[qu]*wV[qv]*base[us[qu]*t1 + vs[qv]];
    }
  ws[OFF_CORR6 + ((size_t)b*9 + p)*65536 + ((size_t)(oy*16+ox)<<8) + t] = fmaxf(s, 0.f);
}

// ---------------------------------------------------------------------------
// 6b) k_cl v2: coalesced transpose via LDS (R14)
__global__ __launch_bounds__(256) void k_cl(float* __restrict__ ws){
  int bx = blockIdx.x;                      // 1024 = b*256 + yx
  int b = bx >> 8, yx = bx & 255;
  const int t = threadIdx.x;
  __shared__ __align__(16) unsigned short tile[10080];   // [yp20][xp21][pr24]
  for (int i=t; i<1260; i+=256)
    *reinterpret_cast<f32x4*>((float*)&tile[i*8]) = (f32x4){0.f,0.f,0.f,0.f};
  __syncthreads();
  const float* c6 = ws + OFF_CORR6 + ((size_t)b*9 << 16) + ((size_t)yx << 8);
  const int qy = t >> 4, qx = t & 15;
  const int wo = ((2+qy)*21 + 2+qx)*24;
  #pragma unroll
  for (int pr=0; pr<9; ++pr)
    tile[wo + pr] = f2bf(c6[((size_t)pr << 16) + t]);
  __syncthreads();
  unsigned short* o = (unsigned short*)(ws + OFF_CL) + (size_t)bx*10080;
  for (int i=t; i<1260; i+=256)
    *reinterpret_cast<f32x4*>((float*)&o[i*8]) =
      *reinterpret_cast<const f32x4*>((const float*)&tile[i*8]);
}

// ---------------------------------------------------------------------------
// 7) chm6d v7: bf16 MFMA implicit GEMM + fused sigmoid/max epilogue (R11)
__global__ __launch_bounds__(256) void k_chm6d(float* __restrict__ ws){
  int id = (blockIdx.x & 7)*128 + (blockIdx.x >> 3);   // XCD swizzle, bijective
  const int b = id >> 8, sy = (id >> 4) & 15, sx = id & 15;
  const int t = threadIdx.x, l = t & 63, w = t >> 6;
  const int x = l & 15, h = (l >> 4) & 1, e2 = (l >> 4) >> 1;
  const unsigned short* CLu = (const unsigned short*)(ws + OFF_CL);
  const unsigned short* WAu = (const unsigned short*)(ws + OFF_WA);
  __shared__ __align__(16) unsigned short tile[2][10080];   // 40,320 B

  f32x4 acc[4];
  #pragma unroll
  for (int i=0;i<4;i++) acc[i] = (f32x4){0.f,0.f,0.f,0.f};

  auto STAGE = [&](int buf, int YX){
    const unsigned short* src = CLu + (size_t)(b*256 + YX)*10080;
    #pragma unroll
    for (int j=0;j<5;++j){
      int ch = t + j*256;
      if (ch < 1260) gl_lds16(src + (size_t)ch*8, &tile[buf][ch*8]);
    }
  };

  const int xb0 = (x + e2)*24 + 8*h;

  int i0 = 0;
  for (; i0 < 25; ++i0){
    int Y = sy + i0/5 - 2, X = sx + i0%5 - 2;
    if (Y>=0 && Y<=15 && X>=0 && X<=15) break;
  }
  {
    int Y = sy + i0/5 - 2, X = sx + i0%5 - 2;
    STAGE(0, Y*16 + X);
  }
  __syncthreads();
  int buf = 0, i = i0;
  #pragma unroll 1
  while (i < 25){
    int nx = i + 1;
    for (; nx < 25; ++nx){
      int Y = sy + nx/5 - 2, X = sx + nx%5 - 2;
      if (Y>=0 && Y<=15 && X>=0 && X<=15) break;
    }
    if (nx < 25){
      int Y = sy + nx/5 - 2, X = sx + nx%5 - 2;
      STAGE(buf^1, Y*16 + X);
    }
    {
      const unsigned short* wa = WAu + (size_t)i*5*3*512;   // [d][kc][lane][8]
      short8v afr[5][3];
      #pragma unroll
      for (int d=0; d<5; ++d)
        #pragma unroll
        for (int kc=0; kc<3; ++kc)
          afr[d][kc] = *(const short8v*)&wa[((d*3 + kc)*64 + l)*8];
      const unsigned short* tb = &tile[buf][0];
      #pragma unroll
      for (int rl=0; rl<8; ++rl){
        const int row = (w*4 + rl)*504;
        short8v bf0 = *(const short8v*)&tb[row + xb0];
        short8v bf1 = *(const short8v*)&tb[row + xb0 + 48];
        short8v bf2 = *(const short8v*)&tb[row + xb0 + 96];
        #pragma unroll
        for (int y=0; y<4; ++y){
          if (y <= rl && rl - y <= 4){
            const int d = rl - y;
            acc[y] = __builtin_amdgcn_mfma_f32_16x16x32_bf16(afr[d][0], bf0, acc[y], 0,0,0);
            acc[y] = __builtin_amdgcn_mfma_f32_16x16x32_bf16(afr[d][1], bf1, acc[y], 0,0,0);
            acc[y] = __builtin_amdgcn_mfma_f32_16x16x32_bf16(afr[d][2], bf2, acc[y], 0,0,0);
          }
        }
      }
    }
    __syncthreads();
    buf ^= 1; i = nx;
  }

  const int g = l >> 4;
  float* maxed = ws + OFF_MAXED + (size_t)b*65536 + (size_t)(sy*16+sx)*256;
  #pragma unroll
  for (int y=0; y<4; ++y){
    float lm;
    if (g < 2)      lm = fmaxf(fmaxf(acc[y][0], acc[y][1]), fmaxf(acc[y][2], acc[y][3]));
    else if (g==2)  lm = acc[y][0];
    else            lm = -1e30f;
    lm = fmaxf(lm, __shfl_xor(lm, 16));
    lm = fmaxf(lm, __shfl_xor(lm, 32));
    if (l < 16)
      maxed[(w*4 + y)*16 + x] = 1.f/(1.f + expf(-lm));
  }
}

// ---------------------------------------------------------------------------
// 8) interpolate4d 16^4 -> 32^4
__global__ void k_interp32(float* __restrict__ ws){
  int id = blockIdx.x*256 + threadIdx.x;
  int px = id & 31, py = (id>>5)&31, ox = (id>>10)&31, oy = (id>>15)&31, b = id>>20;
  int y0,y1,x0,x1,u0,u1,v0,v1; float fy,fx,fu,fv;
  cw_coord(oy,16,32,y0,y1,fy); cw_coord(ox,16,32,x0,x1,fx);
  cw_coord(py,16,32,u0,u1,fu); cw_coord(px,16,32,v0,v1,fv);
  const float* in = ws + OFF_MAXED + (size_t)b*65536;
  int ys[2]={y0,y1}, xs[2]={x0,x1}, us[2]={u0,u1}, vs[2]={v0,v1};
  float wy[2]={1.f-fy,fy}, wx[2]={1.f-fx,fx}, wu[2]={1.f-fu,fu}, wv[2]={1.f-fv,fv};
  float s = 0.f;
  #pragma unroll
  for (int ia=0; ia<2; ia++)
    #pragma unroll
    for (int ic=0; ic<2; ic++){
      float wyx = wy[ia]*wx[ic];
      const float* base = in + ((size_t)ys[ia]*16 + xs[ic])*256;
      #pragma unroll
      for (int id_=0; id_<2; id_++)
        #pragma unroll
        for (int ie=0; ie<2; ie++)
          s += wyx*wu[id_]*wv[ie]*base[(size_t)us[id_]*16 + vs[ie]];
    }
  ws[OFF_INT32 + id] = s;
}

// ---------------------------------------------------------------------------
// 9) fast4d v6: y-split x2. 2048 blocks x 128 thr (2 waves); 20-row dbuf tile;
//    1 barrier/plane; fused partial rowmax -> SMAXP[yh].
__global__ __launch_bounds__(128) void k_fast4d(float* __restrict__ ws,
                                                const float* __restrict__ k4,
                                                const float* __restrict__ b4,
                                                float* __restrict__ out){
  const int bx = blockIdx.x;               // 512 = [sy:5][sxg:3][yh:1]
  const int b = blockIdx.y;
  const int yh = bx & 1;
  const int sy = bx >> 4, sx0 = ((bx >> 1) & 7) << 2;
  const int ybase = yh << 4;
  const int t = threadIdx.x;               // 128
  const int yl = t >> 3, x0 = (t & 7) << 2;
  __shared__ __align__(16) float sQ[2][20*48];
  __shared__ float red[128];
  for (int i=t; i<960; i+=128){ sQ[0][i]=0.f; sQ[1][i]=0.f; }
  __syncthreads();
  const float* in = ws + OFF_INT32 + (size_t)b*1048576;
  float acc[4][4] = {};

  // staging: 160 float4 chunks (20 rows x 8); thread t -> chunk t, t+128(t<32)
  const int r0 = t >> 3, cb0 = t & 7, g0 = ybase - 2 + r0;
  const bool v0 = (g0 >= 0 && g0 <= 31);
  const int c1 = t + 128;
  const int r1 = c1 >> 3, cb1 = c1 & 7, g1 = ybase - 2 + r1;
  const bool v1 = (c1 < 160) && (g1 >= 0 && g1 <= 31);
  const int wo0 = r0*48 + 4 + cb0*4;
  const int wo1 = r1*48 + 4 + cb1*4;

  int i0 = 0;
  for (; i0 < 40; ++i0){
    int Y = sy + (i0>>3) - 2, X = sx0 - 2 + (i0&7);
    if (Y>=0 && Y<=31 && X>=0 && X<=31) break;
  }
  float4 pa = make_float4(0.f,0.f,0.f,0.f), pb = pa;
  if (i0 < 40){
    const float* pl = in + (size_t)((sy+(i0>>3)-2)*32 + sx0-2+(i0&7))*1024;
    if (v0) pa = *reinterpret_cast<const float4*>(pl + g0*32 + cb0*4);
    if (v1) pb = *reinterpret_cast<const float4*>(pl + g1*32 + cb1*4);
  }
  int cur = 0, i = i0;
  #pragma unroll 1
  while (i < 40){
    if (v0) *reinterpret_cast<f32x4*>(&sQ[cur][wo0]) = (f32x4){pa.x,pa.y,pa.z,pa.w};
    if (v1) *reinterpret_cast<f32x4*>(&sQ[cur][wo1]) = (f32x4){pb.x,pb.y,pb.z,pb.w};
    int nx = i+1;
    for (; nx < 40; ++nx){
      int Y = sy + (nx>>3) - 2, X = sx0 - 2 + (nx&7);
      if (Y>=0 && Y<=31 && X>=0 && X<=31) break;
    }
    if (nx < 40){
      const float* pl = in + (size_t)((sy+(nx>>3)-2)*32 + sx0-2+(nx&7))*1024;
      if (v0) pa = *reinterpret_cast<const float4*>(pl + g0*32 + cb0*4);
      if (v1) pb = *reinterpret_cast<const float4*>(pl + g1*32 + cb1*4);
    }
    __syncthreads();
    const int a = i>>3, Xi = i&7;
    const float* ka = k4 + a*125;
    #pragma unroll
    for (int d=0; d<5; d++){
      const float* row = &sQ[cur][(yl+d)*48 + x0];
      float4 q0 = *reinterpret_cast<const float4*>(row);
      float4 q1 = *reinterpret_cast<const float4*>(row+4);
      float4 q2 = *reinterpret_cast<const float4*>(row+8);
      float r12[12] = {q0.x,q0.y,q0.z,q0.w, q1.x,q1.y,q1.z,q1.w,
                       q2.x,q2.y,q2.z,q2.w};
      #pragma unroll
      for (int j=0; j<4; j++){
        const int c = Xi - j;
        if (c >= 0 && c <= 4){
          const float* kc = ka + c*25 + d*5;
          #pragma unroll
          for (int e=0; e<5; e++){
            float wv = kc[e];
            #pragma unroll
            for (int xi=0; xi<4; xi++)
              acc[j][xi] = fmaf(r12[xi+e+2], wv, acc[j][xi]);
          }
        }
      }
    }
    cur ^= 1; i = nx;
  }
  float bias = b4[0];
  const int y = ybase + yl;
  float rmax[4];
  #pragma unroll
  for (int j=0; j<4; j++){
    float4 o;
    float* po = &o.x;
    #pragma unroll
    for (int xi=0; xi<4; xi++){
      float xv = acc[j][xi] + bias;
      po[xi] = fmaxf(xv,0.f) + log1pf(expf(-fabsf(xv)));
    }
    rmax[j] = fmaxf(fmaxf(o.x,o.y), fmaxf(o.z,o.w));
    *reinterpret_cast<float4*>(
      out + ((size_t)b*1024 + sy*32 + sx0 + j)*1024 + y*32 + x0) = o;
  }
  #pragma unroll 1
  for (int j=0; j<4; j++){
    __syncthreads();
    red[t] = rmax[j];
    __syncthreads();
    for (int off=64; off; off>>=1){
      if (t < off) red[t] = fmaxf(red[t], red[t+off]);
      __syncthreads();
    }
    if (!t)
      ws[OFF_SMAXP + (size_t)yh*4096 + (size_t)b*1024 + sy*32 + sx0 + j] = red[0];
  }
}

// ---------------------------------------------------------------------------
// 10-12) mutual_nn_filter
__global__ void k_colmax_p(const float* __restrict__ cm, float* __restrict__ ws){
  int b = blockIdx.x >> 7, rg = (blockIdx.x >> 2) & 31, cg = blockIdx.x & 3;
  int c = cg*256 + threadIdx.x;
  const float* base = cm + (size_t)b*1048576 + (size_t)rg*32768 + c;
  float m = -1e30f;
  #pragma unroll 4
  for (int r=0; r<32; r++) m = fmaxf(m, base[(size_t)r*1024]);
  ws[OFF_CMAXP + (size_t)(b*32+rg)*1024 + c] = m;
}

__global__ void k_colmax_r(float* __restrict__ ws){
  int id = blockIdx.x*256 + threadIdx.x;         // 4096
  int b = id >> 10, c = id & 1023;
  float m = -1e30f;
  #pragma unroll
  for (int rg=0; rg<32; rg++)
    m = fmaxf(m, ws[OFF_CMAXP + (size_t)(b*32+rg)*1024 + c]);
  ws[OFF_TMAX + id] = m;
}

__global__ void k_mutual(float* __restrict__ cm, const float* __restrict__ ws){
  int id = blockIdx.x*256 + threadIdx.x;
  int b = id >> 20, r = (id>>10)&1023, c = id&1023;
  float v  = cm[id];
  float sm = fmaxf(ws[OFF_SMAXP + (b<<10) + r],
                   ws[OFF_SMAXP + 4096 + (b<<10) + r]);
  float tm = ws[OFF_TMAX + (b<<10) + c];
  sm = (sm==0.f) ? 1e-30f : sm;
  tm = (tm==0.f) ? 1e-30f : tm;
  cm[id] = v * (v/sm) * (v/tm);
}

// ---------------------------------------------------------------------------
extern "C" void kernel_launch(void* const* d_in, const int* in_sizes, int n_in,
                              void* d_out, int out_size, void* d_ws, size_t ws_size,
                              hipStream_t stream){
  const float* src = (const float*)d_in[0];
  const float* trg = (const float*)d_in[1];
  const float* w0  = (const float*)d_in[2];
  const float* w1  = (const float*)d_in[3];
  const float* w2  = (const float*)d_in[4];
  const float* k6  = (const float*)d_in[5];
  const float* k4  = (const float*)d_in[6];
  const float* b4  = (const float*)d_in[7];
  float* ws  = (float*)d_ws;    // needs WS_FLOATS*4 = ~72.5 MB
  float* out = (float*)d_out;
  (void)in_sizes; (void)n_in; (void)out_size; (void)ws_size;

  k_wpack       <<<768,   256, 0, stream>>>(w0, w1, w2, ws);
  k_wa          <<<94,    256, 0, stream>>>(k6, ws);
  k_inpack      <<<512,   256, 0, stream>>>(src, trg, ws);
  k_conv_mfma   <<<672,   256, 0, stream>>>(ws);
  k_combine     <<<10752, 256, 0, stream>>>(ws);
  k_fbpack      <<<168,   256, 0, stream>>>(ws);
  k_invnorm     <<<42,    256, 0, stream>>>(ws);
  k_corr        <<<1764,  256, 0, stream>>>(ws);
  k_interp_pairs<<<9216,  256, 0, stream>>>(ws);
  k_cl          <<<1024,  256, 0, stream>>>(ws);
  k_chm6d       <<<1024,  256, 0, stream>>>(ws);
  k_interp32    <<<16384, 256, 0, stream>>>(ws);
  k_fast4d      <<<dim3(512,4),  128, 0, stream>>>(ws, k4, b4, out);
  k_colmax_p    <<<512,   256, 0, stream>>>(out, ws);
  k_colmax_r    <<<16,    256, 0, stream>>>(ws);
  k_mutual      <<<16384, 256, 0, stream>>>(out, ws);
}

// Round 17
// 415.531 us; speedup vs baseline: 1.0733x; 1.0733x over previous
//
#include <hip/hip_runtime.h>
#include <cstdint>
#include <cstddef>

// ============================================================================
// CHMLearner forward. R17: revert fast4d to v4 (R15, measured best) w/ fused
// rowmax; keep 512-block colmax_p; invnorm v3 (16-lane/row shfl reduce).
// ============================================================================

#define DEVFN __device__ __forceinline__

typedef __attribute__((ext_vector_type(8))) short short8v;
typedef __attribute__((ext_vector_type(4))) float f32x4;
typedef unsigned int u32;

DEVFN void gl_lds16(const void* g, void* l){
  __builtin_amdgcn_global_load_lds(
      (const __attribute__((address_space(1))) u32*)g,
      (__attribute__((address_space(3))) u32*)l, 16, 0, 0);
}

// workspace layout (float units). Total ~72.5 MB
constexpr size_t OFF_WB    = 0;           // bf16 packed conv weights
constexpr size_t OFF_P8    = 3538944;     // bf16 padded ch-last features
constexpr size_t OFF_P16   = 3948544;
constexpr size_t OFF_P32   = 5275648;
constexpr size_t OFF_SF8   = 10010624;    // conv outputs f32 [b][256][S*S]
constexpr size_t OFF_TF8   = 10076160;
constexpr size_t OFF_SF16  = 10141696;
constexpr size_t OFF_TF16  = 10403840;
constexpr size_t OFF_SF32  = 10665984;
constexpr size_t OFF_TF32  = 11714560;
constexpr size_t OFF_INVS  = 12763136;
constexpr size_t OFF_INVT  = 12768512;
constexpr size_t OFF_SMAX  = 12773888;    // 4096 rowmax
constexpr size_t OFF_TMAX  = 12777984;    // 4096 colmax
constexpr size_t OFF_CORR6 = 12782080;    // [4][9][16^4] f32
constexpr size_t OFF_CMAXP = OFF_CORR6 + 2359296 + 128;   // 131072 colmax partials
constexpr size_t OFF_WA    = OFF_CMAXP + 131072;          // 192,000 bf16
constexpr size_t OFF_PARTK = OFF_WA + 96128;              // 2,752,512 conv K-partials
constexpr size_t WS_FLOATS = OFF_PARTK + 2752512;

// aliases into dead regions:
__device__ constexpr size_t PAIR_OFF[9] = {   // raw per-pair corr [4][ss^2][ts^2]
  OFF_WB + 0,       OFF_WB + 16384,   OFF_WB + 81920,
  OFF_WB + 344064,  OFF_WB + 409600,  OFF_WB + 671744,
  OFF_WB + 1720320, OFF_WB + 1982464, OFF_WB + 3031040 };
constexpr size_t OFF_CL    = 0;            // bf16 [4][256][20][21][24]
constexpr size_t OFF_MAXED = 9437184;      // [4][16^4] f32
constexpr size_t OFF_INT32 = 262144;       // [4][32^4] f32 (CL dead by interp32)
constexpr size_t OFF_FB    = OFF_PARTK;    // bf16 [10752 rows][256 ch] (PARTK dead)

__device__ constexpr int SSARR[3] = {8, 16, 32};
__device__ constexpr int PAIR_START[9] = {0,4,20,84,100,164,420,484,740}; // 1764

DEVFN unsigned short f2bf(float f){
  unsigned int u = __float_as_uint(f);
  return (unsigned short)((u + 0x7fffu + ((u >> 16) & 1u)) >> 16);
}
DEVFN float bf2f(unsigned short u){
  return __uint_as_float(((unsigned int)u) << 16);
}

// ---------------------------------------------------------------------------
// 1) wpack v2: coalesced via LDS transpose (R13)
__global__ __launch_bounds__(256) void k_wpack(const float* __restrict__ w0,
                                               const float* __restrict__ w1,
                                               const float* __restrict__ w2,
                                               float* __restrict__ wsf){
  int bx = blockIdx.x;
  int scale = bx >> 8, cg = (bx >> 4) & 15, ig = bx & 15;
  const float* w = (scale==0) ? w0 : (scale==1 ? w1 : w2);
  const int t = threadIdx.x;
  __shared__ float sW[16*580];
  const float* src = w + (size_t)cg*16*9216 + (size_t)ig*576;
  for (int i=t; i<9216; i+=256){
    int co = i/576, r = i%576;
    sW[co*580 + r] = src[(size_t)co*9216 + r];
  }
  __syncthreads();
  unsigned short* ob = (unsigned short*)(wsf + OFF_WB) + (size_t)scale*2359296;
  for (int f=t; f<1152; f+=256){
    int tap = f/128, rem = f%128, kcl = rem>>6, l = rem&63;
    int kc = ig*2 + kcl;
    int co = l & 15;
    int ciL = kcl*32 + ((l>>4)&3)*8;
    unsigned short* o = ob + ((size_t)tap*32768 + (size_t)kc*1024 + (size_t)cg*64 + l)*8;
    #pragma unroll
    for (int i=0;i<8;i++)
      o[i] = f2bf(sW[co*580 + (ciL+i)*9 + tap]);
  }
}

// 1b) pack chm6d weights into MFMA A-fragment order
__global__ void k_wa(const float* __restrict__ k6, float* __restrict__ wsf){
  int gid = blockIdx.x*256 + threadIdx.x;        // 24,000
  if (gid >= 24000) return;
  int tap = gid / 192, rem = gid % 192;
  int kc = rem / 64, l = rem % 64;
  int d = tap % 5, ac = tap / 5, a = ac / 5, c = ac % 5;
  int so = l & 15, k8 = (l >> 4) * 8;
  unsigned short* o = (unsigned short*)(wsf + OFF_WA) + (size_t)gid*8;
  #pragma unroll
  for (int i=0;i<8;i++){
    int kg = kc*32 + k8 + i;
    int e = kg >> 4, pr = kg & 15;
    float v = 0.f;
    if (so < 9 && pr < 9 && e < 5){
      int pi = pr/3, pj = pr%3, sio = so/3, sjo = so%3;
      int ki = pi - sio + 1, kj = pj - sjo + 1;
      if (ki>=0 && ki<=2 && kj>=0 && kj<=2)
        v = k6[(((((ki*3+kj)*5 + a)*5 + c)*5 + d)*5) + e];
    }
    o[i] = f2bf(v);
  }
}

// ---------------------------------------------------------------------------
// 2) inpack: stage 16 channels' 16x16 planes in LDS; emit all 3 scales
__global__ __launch_bounds__(256) void k_inpack(const float* __restrict__ src,
                                                const float* __restrict__ trg,
                                                float* __restrict__ wsf){
  int bt = blockIdx.x >> 6, cg = blockIdx.x & 63;
  int chbase = cg*16;
  int t = threadIdx.x;
  __shared__ float sIn[16][257];
  const float* gin = ((bt>=4)? trg : src) + ((size_t)(bt&3)*1024 + chbase)*256;
  #pragma unroll
  for (int i=0;i<16;i++){
    int idx = t + i*256; int ch = idx>>8, pos = idx&255;
    sIn[ch][pos] = gin[(size_t)ch*256 + pos];
  }
  __syncthreads();
  int ch = t & 15, pw = t >> 4;
  #pragma unroll 1
  for (int s=0; s<3; s++){
    int S = SSARR[s], Sp = S+2, Sp2 = Sp*Sp;
    size_t poff = (s==0)?OFF_P8 : (s==1)?OFF_P16 : OFF_P32;
    unsigned short* o = (unsigned short*)(wsf + poff) + (size_t)bt*Sp2*1024 + chbase + ch;
    float rs = 15.f/(float)(S-1);
    for (int i = pw; i < Sp2; i += 16){
      int py = i / Sp, px = i % Sp;
      float v = 0.f;
      if (py>0 && py<Sp-1 && px>0 && px<Sp-1){
        float cy = (float)(py-1)*rs, cx = (float)(px-1)*rs;
        int y0 = (int)cy; if (y0>15) y0=15; int y1 = (y0+1<16)?y0+1:15; float fy = cy-(float)y0;
        int x0 = (int)cx; if (x0>15) x0=15; int x1 = (x0+1<16)?x0+1:15; float fx = cx-(float)x0;
        v = (1.f-fy)*((1.f-fx)*sIn[ch][y0*16+x0] + fx*sIn[ch][y0*16+x1])
          +       fy*((1.f-fx)*sIn[ch][y1*16+x0] + fx*sIn[ch][y1*16+x1]);
      }
      o[(size_t)i*1024] = f2bf(v);
    }
  }
}

// ---------------------------------------------------------------------------
// 3) conv3x3 bf16 MFMA GEMM, K-split x2 (R12)
__global__ __launch_bounds__(256) void k_conv_mfma(float* __restrict__ wsf){
  int bs = (blockIdx.x & 7)*84 + (blockIdx.x >> 3);   // bijective, 672 blocks
  const int ks = bs & 1;
  int bx = bs >> 1;
  int scale, bt, cot, post, S, lgS;
  if (bx < 256)      { scale=2; S=32; lgS=5; bt=bx>>5; cot=(bx>>4)&1; post=bx&15; }
  else if (bx < 320) { int r=bx-256; scale=1; S=16; lgS=4; bt=r>>3; cot=(r>>2)&1; post=r&3; }
  else               { int r=bx-320; scale=0; S=8;  lgS=3; bt=r>>1; cot=r&1; post=0; }
  const int Sp = S+2, N = S*S;
  const unsigned short* WbS = (const unsigned short*)(wsf + OFF_WB) + (size_t)scale*2359296;
  size_t poff = scale==0?OFF_P8: scale==1?OFF_P16:OFF_P32;
  const unsigned short* Pb = (const unsigned short*)(wsf + poff) + (size_t)bt*Sp*Sp*1024;
  size_t obase = (scale==2) ? (bt>=4?OFF_TF32:OFF_SF32)
               : (scale==1) ? (bt>=4?OFF_TF16:OFF_SF16)
                            : (bt>=4?OFF_TF8 :OFF_SF8);
  if (ks) obase += OFF_PARTK - OFF_SF8;
  float* outp = wsf + obase + (size_t)(bt&3)*256*N;

  const int t = threadIdx.x, l = t&63, w = t>>6, wm = w&1, wn = w>>1;
  const int nc_base = cot*8;
  const int pos0 = post*64;
  const int it0 = ks*72, it1 = it0 + 72;

  __shared__ __align__(16) unsigned short Ab[2][8192];   // 32 KB
  __shared__ __align__(16) unsigned short Bb[2][4096];   // 16 KB

  f32x4 acc[4][2];
  #pragma unroll
  for (int i=0;i<4;i++)
    #pragma unroll
    for (int j=0;j<2;j++) acc[i][j] = (f32x4){0.f,0.f,0.f,0.f};

  auto STAGE = [&](int buf, int it){
    int tap = it>>4, kq = it&15;
    int dy = tap/3, dx = tap - dy*3;
    #pragma unroll
    for (int j=0;j<4;++j){
      int c = w + j*4;
      int kc = c>>3, nc = c&7;
      const unsigned short* src =
        WbS + ((((size_t)tap*32 + kq*2 + kc)*16 + nc_base + nc)*64 + l)*8;
      gl_lds16(src, &Ab[buf][c*512]);
    }
    #pragma unroll
    for (int j=0;j<2;++j){
      int c = w + j*4;
      int kc = c>>2, np = c&3;
      int pos = pos0 + np*16 + (l&15);
      int y = pos>>lgS, x = pos&(S-1);
      int row = (y+dy)*Sp + (x+dx);
      int ci = kq*64 + kc*32 + ((l>>4)<<3);
      gl_lds16(Pb + (size_t)row*1024 + ci, &Bb[buf][c*512]);
    }
  };

  STAGE(0, it0);
  __syncthreads();
  int buf = 0;
  #pragma unroll 1
  for (int it=it0; it<it1; ++it){
    if (it+1 < it1) STAGE(buf^1, it+1);
    #pragma unroll
    for (int kc=0; kc<2; ++kc){
      short8v a0 = *(const short8v*)&Ab[buf][((kc*8 + wm*4 + 0)*64 + l)*8];
      short8v a1 = *(const short8v*)&Ab[buf][((kc*8 + wm*4 + 1)*64 + l)*8];
      short8v a2 = *(const short8v*)&Ab[buf][((kc*8 + wm*4 + 2)*64 + l)*8];
      short8v a3 = *(const short8v*)&Ab[buf][((kc*8 + wm*4 + 3)*64 + l)*8];
      short8v b0 = *(const short8v*)&Bb[buf][((kc*4 + wn*2 + 0)*64 + l)*8];
      short8v b1 = *(const short8v*)&Bb[buf][((kc*4 + wn*2 + 1)*64 + l)*8];
      acc[0][0] = __builtin_amdgcn_mfma_f32_16x16x32_bf16(a0, b0, acc[0][0], 0,0,0);
      acc[1][0] = __builtin_amdgcn_mfma_f32_16x16x32_bf16(a1, b0, acc[1][0], 0,0,0);
      acc[2][0] = __builtin_amdgcn_mfma_f32_16x16x32_bf16(a2, b0, acc[2][0], 0,0,0);
      acc[3][0] = __builtin_amdgcn_mfma_f32_16x16x32_bf16(a3, b0, acc[3][0], 0,0,0);
      acc[0][1] = __builtin_amdgcn_mfma_f32_16x16x32_bf16(a0, b1, acc[0][1], 0,0,0);
      acc[1][1] = __builtin_amdgcn_mfma_f32_16x16x32_bf16(a1, b1, acc[1][1], 0,0,0);
      acc[2][1] = __builtin_amdgcn_mfma_f32_16x16x32_bf16(a2, b1, acc[2][1], 0,0,0);
      acc[3][1] = __builtin_amdgcn_mfma_f32_16x16x32_bf16(a3, b1, acc[3][1], 0,0,0);
    }
    __syncthreads();
    buf ^= 1;
  }

  const int r0 = (l>>4)*4, cl = l&15;
  float* ob = outp + (size_t)(cot*128 + wm*64)*N + pos0 + wn*32 + cl;
  #pragma unroll
  for (int mf=0; mf<4; ++mf)
    #pragma unroll
    for (int nf=0; nf<2; ++nf){
      float* op = ob + (size_t)(mf*16 + r0)*N + nf*16;
      #pragma unroll
      for (int i=0;i<4;++i) op[(size_t)i*N] = acc[mf][nf][i];
    }
}

// 3b) combine conv K-partials: outputs += PARTK
__global__ void k_combine(float* __restrict__ ws){
  int i = blockIdx.x*256 + threadIdx.x;          // 2,752,512 exact
  ws[OFF_SF8 + i] += ws[OFF_PARTK + i];
}

// ---------------------------------------------------------------------------
// 3c) fbpack: transpose conv outputs f32 [ch][P] -> FB bf16 [row=pos][256ch]
__global__ __launch_bounds__(256) void k_fbpack(float* __restrict__ ws){
  int bx = blockIdx.x;
  int tsr = bx/84, r = bx%84;
  int s, b, chunk;
  if (r < 4)       { s=0; b=r;        chunk=0; }
  else if (r < 20) { s=1; int q=r-4;  b=q>>2; chunk=q&3; }
  else             { s=2; int q=r-20; b=q>>4; chunk=q&15; }
  int P = SSARR[s]*SSARR[s];
  size_t fbase = (s==0)? (tsr?OFF_TF8 :OFF_SF8)
               : (s==1)? (tsr?OFF_TF16:OFF_SF16)
                       : (tsr?OFF_TF32:OFF_SF32);
  const float* src = ws + fbase + (size_t)b*256*P;
  int pos0 = chunk*64;
  const int t = threadIdx.x;
  __shared__ float tile[64][260];
  for (int i=0;i<64;i++){
    int idx = t + i*256; int ch = idx>>6, pl = idx&63;
    tile[pl][ch] = src[(size_t)ch*P + pos0 + pl];
  }
  __syncthreads();
  int rowbase = tsr*5376 + (s==0?0: s==1?256:1280) + b*P + pos0;
  unsigned short* FB = (unsigned short*)(ws + OFF_FB);
  for (int i=0;i<64;i++){
    int idx = t + i*256; int pl = idx>>8, ch = idx&255;
    FB[(size_t)(rowbase+pl)*256 + ch] = f2bf(tile[pl][ch]);
  }
}

// 4) invnorm v3: 16 lanes per row, shfl reduce. 672 blocks.
__global__ void k_invnorm(float* __restrict__ ws){
  int gid = blockIdx.x*256 + threadIdx.x;        // 172,032 exact
  int row = gid >> 4, sub = gid & 15;
  const unsigned short* fb = (const unsigned short*)(ws + OFF_FB)
                           + (size_t)row*256 + sub*16;
  float s = 0.f;
  #pragma unroll
  for (int i=0;i<2;i++){
    short8v v = *(const short8v*)(fb + i*8);
    #pragma unroll
    for (int j=0;j<8;j++){
      float f = bf2f(((unsigned short*)&v)[j]);
      s = fmaf(f, f, s);
    }
  }
  #pragma unroll
  for (int m=1; m<16; m<<=1) s += __shfl_xor(s, m);
  if (sub == 0){
    int tsr = row/5376, r = row%5376;
    ws[(tsr ? OFF_INVT : OFF_INVS) + r] = 1.f/sqrtf(s);
  }
}

// ---------------------------------------------------------------------------
// 5) corr v2: bf16 MFMA GEMM, 64x64 tiles, K=256, operands direct from FB
__global__ __launch_bounds__(256) void k_corr(float* __restrict__ ws){
  int bx = blockIdx.x;
  int p = (bx>=4)+(bx>=20)+(bx>=84)+(bx>=100)+(bx>=164)+(bx>=420)+(bx>=484)+(bx>=740);
  int si = p/3, ti = p%3;
  int M = SSARR[si]*SSARR[si], N = SSARR[ti]*SSARR[ti];
  int ntN = N >> 6;
  int rem = bx - PAIR_START[p];
  int b = rem & 3; rem >>= 2;
  int nt = rem % ntN, mt = rem / ntN;
  int m0 = mt*64, n0 = nt*64;
  const unsigned short* FB = (const unsigned short*)(ws + OFF_FB);
  const unsigned short* Ap = FB + (size_t)((si==0?0: si==1?256:1280) + b*M + m0)*256;
  const unsigned short* Bp = FB + (size_t)(5376 + (ti==0?0: ti==1?256:1280) + b*N + n0)*256;
  const int t = threadIdx.x, l = t&63, w = t>>6, wm = w&1, wn = w>>1;
  const int mrow = wm*32 + (l&15), ncol = wn*32 + (l&15);
  f32x4 acc[2][2];
  #pragma unroll
  for (int i=0;i<2;i++)
    #pragma unroll
    for (int j=0;j<2;j++) acc[i][j] = (f32x4){0.f,0.f,0.f,0.f};
  #pragma unroll
  for (int ksp=0; ksp<8; ++ksp){
    const int ko = ksp*32 + ((l>>4)&3)*8;
    short8v a0 = *(const short8v*)(Ap + (size_t) mrow     *256 + ko);
    short8v a1 = *(const short8v*)(Ap + (size_t)(mrow+16) *256 + ko);
    short8v b0 = *(const short8v*)(Bp + (size_t) ncol     *256 + ko);
    short8v b1 = *(const short8v*)(Bp + (size_t)(ncol+16) *256 + ko);
    acc[0][0] = __builtin_amdgcn_mfma_f32_16x16x32_bf16(a0, b0, acc[0][0], 0,0,0);
    acc[1][0] = __builtin_amdgcn_mfma_f32_16x16x32_bf16(a1, b0, acc[1][0], 0,0,0);
    acc[0][1] = __builtin_amdgcn_mfma_f32_16x16x32_bf16(a0, b1, acc[0][1], 0,0,0);
    acc[1][1] = __builtin_amdgcn_mfma_f32_16x16x32_bf16(a1, b1, acc[1][1], 0,0,0);
  }
  const float* iS = ws + OFF_INVS + (si==0?0: si==1?256:1280) + (size_t)b*M;
  const float* iT = ws + OFF_INVT + (ti==0?0: ti==1?256:1280) + (size_t)b*N;
  float* C = ws + PAIR_OFF[p] + (size_t)b*M*N;
  const int r0 = (l>>4)*4, cl = l&15;
  #pragma unroll
  for (int mf=0; mf<2; ++mf)
    #pragma unroll
    for (int nf=0; nf<2; ++nf)
      #pragma unroll
      for (int i=0;i<4;++i){
        int m = m0 + wm*32 + mf*16 + r0 + i;
        int n = n0 + wn*32 + nf*16 + cl;
        C[(size_t)m*N + n] = acc[mf][nf][i]*iS[m]*iT[n];
      }
}

// ---------------------------------------------------------------------------
DEVFN void cw_coord(int i, int n, int OH, int& i0, int& i1, float& f){
  float c = (float)(i*(n-1))/(float)(OH-1);
  int a = (int)c; if (a > n-1) a = n-1;
  i0 = a; i1 = (a+1 < n) ? a+1 : n-1; f = c - (float)a;
}

// 6) interp_pairs v2: block = (p,b,oy,ox); stage 4 corner (y,x) planes in LDS
__global__ __launch_bounds__(256) void k_interp_pairs(float* __restrict__ ws){
  int bx = blockIdx.x;
  int p = bx >> 10;
  int bl = bx & 1023;                    // [b:2][oy:4][ox:4]
  int b = bl >> 8, oy = (bl >> 4) & 15, ox = bl & 15;
  int si = p/3, ti = p%3;
  int h1 = SSARR[si], t1 = SSARR[ti], t12 = t1*t1;
  int y0,y1,x0,x1; float fy,fx;
  cw_coord(oy,h1,16,y0,y1,fy); cw_coord(ox,h1,16,x0,x1,fx);
  const float* in = ws + PAIR_OFF[p] + (size_t)b*h1*h1*t12;
  __shared__ float sPl[4][1024];
  const int t = threadIdx.x;
  {
    const float* pl0 = in + (size_t)(y0*h1+x0)*t12;
    const float* pl1 = in + (size_t)(y0*h1+x1)*t12;
    const float* pl2 = in + (size_t)(y1*h1+x0)*t12;
    const float* pl3 = in + (size_t)(y1*h1+x1)*t12;
    for (int i=t; i<t12; i+=256){
      sPl[0][i] = pl0[i]; sPl[1][i] = pl1[i];
      sPl[2][i] = pl2[i]; sPl[3][i] = pl3[i];
    }
  }
  __syncthreads();
  int px = t & 15, py = t >> 4;
  int u0,u1,v0,v1; float fu,fv;
  cw_coord(py,t1,16,u0,u1,fu); cw_coord(px,t1,16,v0,v1,fv);
  float wY[2]={1.f-fy,fy}, wX[2]={1.f-fx,fx};
  float wU[2]={1.f-fu,fu}, wV[2]={1.f-fv,fv};
  int us[2]={u0,u1}, vs[2]={v0,v1};
  float s = 0.f;
  #pragma unroll
  for (int qa=0; qa<2; qa++)
    #pragma unroll
    for (int qc=0; qc<2; qc++){
      float wyx = wY[qa]*wX[qc];
      const float* base = sPl[qa*2+qc];
      #pragma unroll
      for (int qu=0; qu<2; qu++)
        #pragma unroll
        for (int qv=0; qv<2; qv++)
          s += wyx*wU[qu]*wV[qv]*base[us[qu]*t1 + vs[qv]];
    }
  ws[OFF_CORR6 + ((size_t)b*9 + p)*65536 + ((size_t)(oy*16+ox)<<8) + t] = fmaxf(s, 0.f);
}

// ---------------------------------------------------------------------------
// 6b) k_cl v2: coalesced transpose via LDS (R14)
__global__ __launch_bounds__(256) void k_cl(float* __restrict__ ws){
  int bx = blockIdx.x;                      // 1024 = b*256 + yx
  int b = bx >> 8, yx = bx & 255;
  const int t = threadIdx.x;
  __shared__ __align__(16) unsigned short tile[10080];   // [yp20][xp21][pr24]
  for (int i=t; i<1260; i+=256)
    *reinterpret_cast<f32x4*>((float*)&tile[i*8]) = (f32x4){0.f,0.f,0.f,0.f};
  __syncthreads();
  const float* c6 = ws + OFF_CORR6 + ((size_t)b*9 << 16) + ((size_t)yx << 8);
  const int qy = t >> 4, qx = t & 15;
  const int wo = ((2+qy)*21 + 2+qx)*24;
  #pragma unroll
  for (int pr=0; pr<9; ++pr)
    tile[wo + pr] = f2bf(c6[((size_t)pr << 16) + t]);
  __syncthreads();
  unsigned short* o = (unsigned short*)(ws + OFF_CL) + (size_t)bx*10080;
  for (int i=t; i<1260; i+=256)
    *reinterpret_cast<f32x4*>((float*)&o[i*8]) =
      *reinterpret_cast<const f32x4*>((const float*)&tile[i*8]);
}

// ---------------------------------------------------------------------------
// 7) chm6d v7: bf16 MFMA implicit GEMM + fused sigmoid/max epilogue (R11)
__global__ __launch_bounds__(256) void k_chm6d(float* __restrict__ ws){
  int id = (blockIdx.x & 7)*128 + (blockIdx.x >> 3);   // XCD swizzle, bijective
  const int b = id >> 8, sy = (id >> 4) & 15, sx = id & 15;
  const int t = threadIdx.x, l = t & 63, w = t >> 6;
  const int x = l & 15, h = (l >> 4) & 1, e2 = (l >> 4) >> 1;
  const unsigned short* CLu = (const unsigned short*)(ws + OFF_CL);
  const unsigned short* WAu = (const unsigned short*)(ws + OFF_WA);
  __shared__ __align__(16) unsigned short tile[2][10080];   // 40,320 B

  f32x4 acc[4];
  #pragma unroll
  for (int i=0;i<4;i++) acc[i] = (f32x4){0.f,0.f,0.f,0.f};

  auto STAGE = [&](int buf, int YX){
    const unsigned short* src = CLu + (size_t)(b*256 + YX)*10080;
    #pragma unroll
    for (int j=0;j<5;++j){
      int ch = t + j*256;
      if (ch < 1260) gl_lds16(src + (size_t)ch*8, &tile[buf][ch*8]);
    }
  };

  const int xb0 = (x + e2)*24 + 8*h;

  int i0 = 0;
  for (; i0 < 25; ++i0){
    int Y = sy + i0/5 - 2, X = sx + i0%5 - 2;
    if (Y>=0 && Y<=15 && X>=0 && X<=15) break;
  }
  {
    int Y = sy + i0/5 - 2, X = sx + i0%5 - 2;
    STAGE(0, Y*16 + X);
  }
  __syncthreads();
  int buf = 0, i = i0;
  #pragma unroll 1
  while (i < 25){
    int nx = i + 1;
    for (; nx < 25; ++nx){
      int Y = sy + nx/5 - 2, X = sx + nx%5 - 2;
      if (Y>=0 && Y<=15 && X>=0 && X<=15) break;
    }
    if (nx < 25){
      int Y = sy + nx/5 - 2, X = sx + nx%5 - 2;
      STAGE(buf^1, Y*16 + X);
    }
    {
      const unsigned short* wa = WAu + (size_t)i*5*3*512;   // [d][kc][lane][8]
      short8v afr[5][3];
      #pragma unroll
      for (int d=0; d<5; ++d)
        #pragma unroll
        for (int kc=0; kc<3; ++kc)
          afr[d][kc] = *(const short8v*)&wa[((d*3 + kc)*64 + l)*8];
      const unsigned short* tb = &tile[buf][0];
      #pragma unroll
      for (int rl=0; rl<8; ++rl){
        const int row = (w*4 + rl)*504;
        short8v bf0 = *(const short8v*)&tb[row + xb0];
        short8v bf1 = *(const short8v*)&tb[row + xb0 + 48];
        short8v bf2 = *(const short8v*)&tb[row + xb0 + 96];
        #pragma unroll
        for (int y=0; y<4; ++y){
          if (y <= rl && rl - y <= 4){
            const int d = rl - y;
            acc[y] = __builtin_amdgcn_mfma_f32_16x16x32_bf16(afr[d][0], bf0, acc[y], 0,0,0);
            acc[y] = __builtin_amdgcn_mfma_f32_16x16x32_bf16(afr[d][1], bf1, acc[y], 0,0,0);
            acc[y] = __builtin_amdgcn_mfma_f32_16x16x32_bf16(afr[d][2], bf2, acc[y], 0,0,0);
          }
        }
      }
    }
    __syncthreads();
    buf ^= 1; i = nx;
  }

  const int g = l >> 4;
  float* maxed = ws + OFF_MAXED + (size_t)b*65536 + (size_t)(sy*16+sx)*256;
  #pragma unroll
  for (int y=0; y<4; ++y){
    float lm;
    if (g < 2)      lm = fmaxf(fmaxf(acc[y][0], acc[y][1]), fmaxf(acc[y][2], acc[y][3]));
    else if (g==2)  lm = acc[y][0];
    else            lm = -1e30f;
    lm = fmaxf(lm, __shfl_xor(lm, 16));
    lm = fmaxf(lm, __shfl_xor(lm, 32));
    if (l < 16)
      maxed[(w*4 + y)*16 + x] = 1.f/(1.f + expf(-lm));
  }
}

// ---------------------------------------------------------------------------
// 8) interpolate4d 16^4 -> 32^4
__global__ void k_interp32(float* __restrict__ ws){
  int id = blockIdx.x*256 + threadIdx.x;
  int px = id & 31, py = (id>>5)&31, ox = (id>>10)&31, oy = (id>>15)&31, b = id>>20;
  int y0,y1,x0,x1,u0,u1,v0,v1; float fy,fx,fu,fv;
  cw_coord(oy,16,32,y0,y1,fy); cw_coord(ox,16,32,x0,x1,fx);
  cw_coord(py,16,32,u0,u1,fu); cw_coord(px,16,32,v0,v1,fv);
  const float* in = ws + OFF_MAXED + (size_t)b*65536;
  int ys[2]={y0,y1}, xs[2]={x0,x1}, us[2]={u0,u1}, vs[2]={v0,v1};
  float wy[2]={1.f-fy,fy}, wx[2]={1.f-fx,fx}, wu[2]={1.f-fu,fu}, wv[2]={1.f-fv,fv};
  float s = 0.f;
  #pragma unroll
  for (int ia=0; ia<2; ia++)
    #pragma unroll
    for (int ic=0; ic<2; ic++){
      float wyx = wy[ia]*wx[ic];
      const float* base = in + ((size_t)ys[ia]*16 + xs[ic])*256;
      #pragma unroll
      for (int id_=0; id_<2; id_++)
        #pragma unroll
        for (int ie=0; ie<2; ie++)
          s += wyx*wu[id_]*wv[ie]*base[(size_t)us[id_]*16 + vs[ie]];
    }
  ws[OFF_INT32 + id] = s;
}

// ---------------------------------------------------------------------------
// 9) fast4d v4 (R15, measured best) + fused rowmax epilogue -> SMAX
__global__ __launch_bounds__(256) void k_fast4d(float* __restrict__ ws,
                                                const float* __restrict__ k4,
                                                const float* __restrict__ b4,
                                                float* __restrict__ out){
  const int b = blockIdx.y;
  const int sy = blockIdx.x >> 3, sx0 = (blockIdx.x & 7) << 2;
  const int t = threadIdx.x;
  const int y = t >> 3, x0 = (t & 7) << 2;
  __shared__ __align__(16) float sQ[2][36*48];
  __shared__ float red[256];
  for (int i=t; i<1728; i+=256){ sQ[0][i]=0.f; sQ[1][i]=0.f; }
  __syncthreads();
  const float* in = ws + OFF_INT32 + (size_t)b*1048576;
  float acc[4][4] = {};

  int i0 = 0;
  for (; i0 < 40; ++i0){
    int Y = sy + (i0>>3) - 2, X = sx0 - 2 + (i0&7);
    if (Y>=0 && Y<=31 && X>=0 && X<=31) break;
  }
  float4 pf = make_float4(0.f,0.f,0.f,0.f);
  if (i0 < 40){
    int Y = sy + (i0>>3) - 2, X = sx0 - 2 + (i0&7);
    pf = *reinterpret_cast<const float4*>(in + (size_t)(Y*32+X)*1024 + t*4);
  }
  int cur = 0, i = i0;
  const int srow = t >> 3, scol4 = (t & 7) << 2;
  const int wo = (2+srow)*48 + 4 + scol4;          // aligned b128 write
  #pragma unroll 1
  while (i < 40){
    int nx = i+1;
    for (; nx < 40; ++nx){
      int Y = sy + (nx>>3) - 2, X = sx0 - 2 + (nx&7);
      if (Y>=0 && Y<=31 && X>=0 && X<=31) break;
    }
    *reinterpret_cast<f32x4*>(&sQ[cur][wo]) = (f32x4){pf.x,pf.y,pf.z,pf.w};
    if (nx < 40){
      int Y = sy + (nx>>3) - 2, X = sx0 - 2 + (nx&7);
      pf = *reinterpret_cast<const float4*>(in + (size_t)(Y*32+X)*1024 + t*4);
    }
    __syncthreads();
    const int a = i>>3, Xi = i&7;
    const float* ka = k4 + a*125;
    #pragma unroll
    for (int d=0; d<5; d++){
      const float* row = &sQ[cur][(y+d)*48 + x0];
      float4 q0 = *reinterpret_cast<const float4*>(row);
      float4 q1 = *reinterpret_cast<const float4*>(row+4);
      float4 q2 = *reinterpret_cast<const float4*>(row+8);
      float r12[12] = {q0.x,q0.y,q0.z,q0.w, q1.x,q1.y,q1.z,q1.w,
                       q2.x,q2.y,q2.z,q2.w};
      #pragma unroll
      for (int j=0; j<4; j++){
        const int c = Xi - j;
        if (c >= 0 && c <= 4){
          const float* kc = ka + c*25 + d*5;
          #pragma unroll
          for (int e=0; e<5; e++){
            float wv = kc[e];
            #pragma unroll
            for (int xi=0; xi<4; xi++)
              acc[j][xi] = fmaf(r12[xi+e+2], wv, acc[j][xi]);
          }
        }
      }
    }
    cur ^= 1; i = nx;
  }
  float bias = b4[0];
  float rmax[4];
  #pragma unroll
  for (int j=0; j<4; j++){
    float4 o;
    float* po = &o.x;
    #pragma unroll
    for (int xi=0; xi<4; xi++){
      float xv = acc[j][xi] + bias;
      po[xi] = fmaxf(xv,0.f) + log1pf(expf(-fabsf(xv)));
    }
    rmax[j] = fmaxf(fmaxf(o.x,o.y), fmaxf(o.z,o.w));
    *reinterpret_cast<float4*>(
      out + ((size_t)b*1024 + sy*32 + sx0 + j)*1024 + y*32 + x0) = o;
  }
  #pragma unroll 1
  for (int j=0; j<4; j++){
    __syncthreads();
    red[t] = rmax[j];
    __syncthreads();
    for (int off=128; off; off>>=1){
      if (t < off) red[t] = fmaxf(red[t], red[t+off]);
      __syncthreads();
    }
    if (!t) ws[OFF_SMAX + (size_t)b*1024 + sy*32 + sx0 + j] = red[0];
  }
}

// ---------------------------------------------------------------------------
// 10-12) mutual_nn_filter (rowmax fused into fast4d)
__global__ void k_colmax_p(const float* __restrict__ cm, float* __restrict__ ws){
  int b = blockIdx.x >> 7, rg = (blockIdx.x >> 2) & 31, cg = blockIdx.x & 3;
  int c = cg*256 + threadIdx.x;
  const float* base = cm + (size_t)b*1048576 + (size_t)rg*32768 + c;
  float m = -1e30f;
  #pragma unroll 4
  for (int r=0; r<32; r++) m = fmaxf(m, base[(size_t)r*1024]);
  ws[OFF_CMAXP + (size_t)(b*32+rg)*1024 + c] = m;
}

__global__ void k_colmax_r(float* __restrict__ ws){
  int id = blockIdx.x*256 + threadIdx.x;         // 4096
  int b = id >> 10, c = id & 1023;
  float m = -1e30f;
  #pragma unroll
  for (int rg=0; rg<32; rg++)
    m = fmaxf(m, ws[OFF_CMAXP + (size_t)(b*32+rg)*1024 + c]);
  ws[OFF_TMAX + id] = m;
}

__global__ void k_mutual(float* __restrict__ cm, const float* __restrict__ ws){
  int id = blockIdx.x*256 + threadIdx.x;
  int b = id >> 20, r = (id>>10)&1023, c = id&1023;
  float v  = cm[id];
  float sm = ws[OFF_SMAX + (b<<10) + r];
  float tm = ws[OFF_TMAX + (b<<10) + c];
  sm = (sm==0.f) ? 1e-30f : sm;
  tm = (tm==0.f) ? 1e-30f : tm;
  cm[id] = v * (v/sm) * (v/tm);
}

// ---------------------------------------------------------------------------
extern "C" void kernel_launch(void* const* d_in, const int* in_sizes, int n_in,
                              void* d_out, int out_size, void* d_ws, size_t ws_size,
                              hipStream_t stream){
  const float* src = (const float*)d_in[0];
  const float* trg = (const float*)d_in[1];
  const float* w0  = (const float*)d_in[2];
  const float* w1  = (const float*)d_in[3];
  const float* w2  = (const float*)d_in[4];
  const float* k6  = (const float*)d_in[5];
  const float* k4  = (const float*)d_in[6];
  const float* b4  = (const float*)d_in[7];
  float* ws  = (float*)d_ws;    // needs WS_FLOATS*4 = ~72.5 MB
  float* out = (float*)d_out;
  (void)in_sizes; (void)n_in; (void)out_size; (void)ws_size;

  k_wpack       <<<768,   256, 0, stream>>>(w0, w1, w2, ws);
  k_wa          <<<94,    256, 0, stream>>>(k6, ws);
  k_inpack      <<<512,   256, 0, stream>>>(src, trg, ws);
  k_conv_mfma   <<<672,   256, 0, stream>>>(ws);
  k_combine     <<<10752, 256, 0, stream>>>(ws);
  k_fbpack      <<<168,   256, 0, stream>>>(ws);
  k_invnorm     <<<672,   256, 0, stream>>>(ws);
  k_corr        <<<1764,  256, 0, stream>>>(ws);
  k_interp_pairs<<<9216,  256, 0, stream>>>(ws);
  k_cl          <<<1024,  256, 0, stream>>>(ws);
  k_chm6d       <<<1024,  256, 0, stream>>>(ws);
  k_interp32    <<<16384, 256, 0, stream>>>(ws);
  k_fast4d      <<<dim3(256,4),  256, 0, stream>>>(ws, k4, b4, out);
  k_colmax_p    <<<512,   256, 0, stream>>>(out, ws);
  k_colmax_r    <<<16,    256, 0, stream>>>(ws);
  k_mutual      <<<16384, 256, 0, stream>>>(out, ws);
}

// Round 18
// 377.078 us; speedup vs baseline: 1.1827x; 1.1020x over previous
//
#include <hip/hip_runtime.h>
#include <cstdint>
#include <cstddef>

// ============================================================================
// CHMLearner forward. R18: fast4d v7 — bf16 MFMA implicit GEMM (M=16 source
// shifts, N=16 x, K=(e,plane-window)=320 per d; channels-last LDS tile,
// packed WA4 weights, fused softplus+rowmax partials). Rest identical to R17.
// ============================================================================

#define DEVFN __device__ __forceinline__

typedef __attribute__((ext_vector_type(8))) short short8v;
typedef __attribute__((ext_vector_type(4))) float f32x4;
typedef unsigned int u32;

DEVFN void gl_lds16(const void* g, void* l){
  __builtin_amdgcn_global_load_lds(
      (const __attribute__((address_space(1))) u32*)g,
      (__attribute__((address_space(3))) u32*)l, 16, 0, 0);
}

// workspace layout (float units). Total ~72.6 MB
constexpr size_t OFF_WB    = 0;           // bf16 packed conv weights
constexpr size_t OFF_P8    = 3538944;     // bf16 padded ch-last features
constexpr size_t OFF_P16   = 3948544;
constexpr size_t OFF_P32   = 5275648;
constexpr size_t OFF_SF8   = 10010624;    // conv outputs f32 [b][256][S*S]
constexpr size_t OFF_TF8   = 10076160;
constexpr size_t OFF_SF16  = 10141696;
constexpr size_t OFF_TF16  = 10403840;
constexpr size_t OFF_SF32  = 10665984;
constexpr size_t OFF_TF32  = 11714560;
constexpr size_t OFF_INVS  = 12763136;
constexpr size_t OFF_INVT  = 12768512;
constexpr size_t OFF_TMAX  = 12777984;    // 4096 colmax
constexpr size_t OFF_CORR6 = 12782080;    // [4][9][16^4] f32
constexpr size_t OFF_CMAXP = OFF_CORR6 + 2359296 + 128;   // 131072 colmax partials
constexpr size_t OFF_WA    = OFF_CMAXP + 131072;          // 192,000 bf16
constexpr size_t OFF_PARTK = OFF_WA + 96128;              // 2,752,512 conv K-partials
constexpr size_t OFF_SMAXP = OFF_PARTK + 2752512;         // [4yh][4b][1024] rowmax
constexpr size_t OFF_WA4   = OFF_SMAXP + 16384;           // 25,600 bf16 = 12,800 f
constexpr size_t WS_FLOATS = OFF_WA4 + 12800;

// aliases into dead regions:
__device__ constexpr size_t PAIR_OFF[9] = {   // raw per-pair corr [4][ss^2][ts^2]
  OFF_WB + 0,       OFF_WB + 16384,   OFF_WB + 81920,
  OFF_WB + 344064,  OFF_WB + 409600,  OFF_WB + 671744,
  OFF_WB + 1720320, OFF_WB + 1982464, OFF_WB + 3031040 };
constexpr size_t OFF_CL    = 0;            // bf16 [4][256][20][21][24]
constexpr size_t OFF_MAXED = 9437184;      // [4][16^4] f32
constexpr size_t OFF_INT32 = 262144;       // [4][32^4] f32 (CL dead by interp32)
constexpr size_t OFF_FB    = OFF_PARTK;    // bf16 [10752 rows][256 ch] (PARTK dead)

__device__ constexpr int SSARR[3] = {8, 16, 32};
__device__ constexpr int PAIR_START[9] = {0,4,20,84,100,164,420,484,740}; // 1764

DEVFN unsigned short f2bf(float f){
  unsigned int u = __float_as_uint(f);
  return (unsigned short)((u + 0x7fffu + ((u >> 16) & 1u)) >> 16);
}
DEVFN float bf2f(unsigned short u){
  return __uint_as_float(((unsigned int)u) << 16);
}

// ---------------------------------------------------------------------------
// 1) wpack v2: coalesced via LDS transpose (R13)
__global__ __launch_bounds__(256) void k_wpack(const float* __restrict__ w0,
                                               const float* __restrict__ w1,
                                               const float* __restrict__ w2,
                                               float* __restrict__ wsf){
  int bx = blockIdx.x;
  int scale = bx >> 8, cg = (bx >> 4) & 15, ig = bx & 15;
  const float* w = (scale==0) ? w0 : (scale==1 ? w1 : w2);
  const int t = threadIdx.x;
  __shared__ float sW[16*580];
  const float* src = w + (size_t)cg*16*9216 + (size_t)ig*576;
  for (int i=t; i<9216; i+=256){
    int co = i/576, r = i%576;
    sW[co*580 + r] = src[(size_t)co*9216 + r];
  }
  __syncthreads();
  unsigned short* ob = (unsigned short*)(wsf + OFF_WB) + (size_t)scale*2359296;
  for (int f=t; f<1152; f+=256){
    int tap = f/128, rem = f%128, kcl = rem>>6, l = rem&63;
    int kc = ig*2 + kcl;
    int co = l & 15;
    int ciL = kcl*32 + ((l>>4)&3)*8;
    unsigned short* o = ob + ((size_t)tap*32768 + (size_t)kc*1024 + (size_t)cg*64 + l)*8;
    #pragma unroll
    for (int i=0;i<8;i++)
      o[i] = f2bf(sW[co*580 + (ciL+i)*9 + tap]);
  }
}

// 1b) pack chm6d weights into MFMA A-fragment order
__global__ void k_wa(const float* __restrict__ k6, float* __restrict__ wsf){
  int gid = blockIdx.x*256 + threadIdx.x;        // 24,000
  if (gid >= 24000) return;
  int tap = gid / 192, rem = gid % 192;
  int kc = rem / 64, l = rem % 64;
  int d = tap % 5, ac = tap / 5, a = ac / 5, c = ac % 5;
  int so = l & 15, k8 = (l >> 4) * 8;
  unsigned short* o = (unsigned short*)(wsf + OFF_WA) + (size_t)gid*8;
  #pragma unroll
  for (int i=0;i<8;i++){
    int kg = kc*32 + k8 + i;
    int e = kg >> 4, pr = kg & 15;
    float v = 0.f;
    if (so < 9 && pr < 9 && e < 5){
      int pi = pr/3, pj = pr%3, sio = so/3, sjo = so%3;
      int ki = pi - sio + 1, kj = pj - sjo + 1;
      if (ki>=0 && ki<=2 && kj>=0 && kj<=2)
        v = k6[(((((ki*3+kj)*5 + a)*5 + c)*5 + d)*5) + e];
    }
    o[i] = f2bf(v);
  }
}

// 1c) pack fast4d weights: WA4[d][kc][lane][8]
//     A[so=(soy,sox)][k=(e,pyw,pxw)] = k4[pyw-soy][pxw-sox][d][e] (valid window)
__global__ void k_wa4(const float* __restrict__ k4, float* __restrict__ wsf){
  int gid = blockIdx.x*256 + threadIdx.x;        // 3200 = 5d*10kc*64l
  if (gid >= 3200) return;
  int d = gid / 640, rem = gid % 640;
  int kc = rem / 64, l = rem % 64;
  int so = l & 15, soy = so >> 2, sox = so & 3;
  int e = kc >> 1;
  int pyw = 4*(kc & 1) + (l >> 4);
  unsigned short* o = (unsigned short*)(wsf + OFF_WA4) + (size_t)gid*8;
  #pragma unroll
  for (int i=0;i<8;i++){
    int a = pyw - soy, c = i - sox;
    float v = 0.f;
    if (a>=0 && a<=4 && c>=0 && c<=4)
      v = k4[((a*5 + c)*5 + d)*5 + e];
    o[i] = f2bf(v);
  }
}

// ---------------------------------------------------------------------------
// 2) inpack: stage 16 channels' 16x16 planes in LDS; emit all 3 scales
__global__ __launch_bounds__(256) void k_inpack(const float* __restrict__ src,
                                                const float* __restrict__ trg,
                                                float* __restrict__ wsf){
  int bt = blockIdx.x >> 6, cg = blockIdx.x & 63;
  int chbase = cg*16;
  int t = threadIdx.x;
  __shared__ float sIn[16][257];
  const float* gin = ((bt>=4)? trg : src) + ((size_t)(bt&3)*1024 + chbase)*256;
  #pragma unroll
  for (int i=0;i<16;i++){
    int idx = t + i*256; int ch = idx>>8, pos = idx&255;
    sIn[ch][pos] = gin[(size_t)ch*256 + pos];
  }
  __syncthreads();
  int ch = t & 15, pw = t >> 4;
  #pragma unroll 1
  for (int s=0; s<3; s++){
    int S = SSARR[s], Sp = S+2, Sp2 = Sp*Sp;
    size_t poff = (s==0)?OFF_P8 : (s==1)?OFF_P16 : OFF_P32;
    unsigned short* o = (unsigned short*)(wsf + poff) + (size_t)bt*Sp2*1024 + chbase + ch;
    float rs = 15.f/(float)(S-1);
    for (int i = pw; i < Sp2; i += 16){
      int py = i / Sp, px = i % Sp;
      float v = 0.f;
      if (py>0 && py<Sp-1 && px>0 && px<Sp-1){
        float cy = (float)(py-1)*rs, cx = (float)(px-1)*rs;
        int y0 = (int)cy; if (y0>15) y0=15; int y1 = (y0+1<16)?y0+1:15; float fy = cy-(float)y0;
        int x0 = (int)cx; if (x0>15) x0=15; int x1 = (x0+1<16)?x0+1:15; float fx = cx-(float)x0;
        v = (1.f-fy)*((1.f-fx)*sIn[ch][y0*16+x0] + fx*sIn[ch][y0*16+x1])
          +       fy*((1.f-fx)*sIn[ch][y1*16+x0] + fx*sIn[ch][y1*16+x1]);
      }
      o[(size_t)i*1024] = f2bf(v);
    }
  }
}

// ---------------------------------------------------------------------------
// 3) conv3x3 bf16 MFMA GEMM, K-split x2 (R12)
__global__ __launch_bounds__(256) void k_conv_mfma(float* __restrict__ wsf){
  int bs = (blockIdx.x & 7)*84 + (blockIdx.x >> 3);   // bijective, 672 blocks
  const int ks = bs & 1;
  int bx = bs >> 1;
  int scale, bt, cot, post, S, lgS;
  if (bx < 256)      { scale=2; S=32; lgS=5; bt=bx>>5; cot=(bx>>4)&1; post=bx&15; }
  else if (bx < 320) { int r=bx-256; scale=1; S=16; lgS=4; bt=r>>3; cot=(r>>2)&1; post=r&3; }
  else               { int r=bx-320; scale=0; S=8;  lgS=3; bt=r>>1; cot=r&1; post=0; }
  const int Sp = S+2, N = S*S;
  const unsigned short* WbS = (const unsigned short*)(wsf + OFF_WB) + (size_t)scale*2359296;
  size_t poff = scale==0?OFF_P8: scale==1?OFF_P16:OFF_P32;
  const unsigned short* Pb = (const unsigned short*)(wsf + poff) + (size_t)bt*Sp*Sp*1024;
  size_t obase = (scale==2) ? (bt>=4?OFF_TF32:OFF_SF32)
               : (scale==1) ? (bt>=4?OFF_TF16:OFF_SF16)
                            : (bt>=4?OFF_TF8 :OFF_SF8);
  if (ks) obase += OFF_PARTK - OFF_SF8;
  float* outp = wsf + obase + (size_t)(bt&3)*256*N;

  const int t = threadIdx.x, l = t&63, w = t>>6, wm = w&1, wn = w>>1;
  const int nc_base = cot*8;
  const int pos0 = post*64;
  const int it0 = ks*72, it1 = it0 + 72;

  __shared__ __align__(16) unsigned short Ab[2][8192];   // 32 KB
  __shared__ __align__(16) unsigned short Bb[2][4096];   // 16 KB

  f32x4 acc[4][2];
  #pragma unroll
  for (int i=0;i<4;i++)
    #pragma unroll
    for (int j=0;j<2;j++) acc[i][j] = (f32x4){0.f,0.f,0.f,0.f};

  auto STAGE = [&](int buf, int it){
    int tap = it>>4, kq = it&15;
    int dy = tap/3, dx = tap - dy*3;
    #pragma unroll
    for (int j=0;j<4;++j){
      int c = w + j*4;
      int kc = c>>3, nc = c&7;
      const unsigned short* src =
        WbS + ((((size_t)tap*32 + kq*2 + kc)*16 + nc_base + nc)*64 + l)*8;
      gl_lds16(src, &Ab[buf][c*512]);
    }
    #pragma unroll
    for (int j=0;j<2;++j){
      int c = w + j*4;
      int kc = c>>2, np = c&3;
      int pos = pos0 + np*16 + (l&15);
      int y = pos>>lgS, x = pos&(S-1);
      int row = (y+dy)*Sp + (x+dx);
      int ci = kq*64 + kc*32 + ((l>>4)<<3);
      gl_lds16(Pb + (size_t)row*1024 + ci, &Bb[buf][c*512]);
    }
  };

  STAGE(0, it0);
  __syncthreads();
  int buf = 0;
  #pragma unroll 1
  for (int it=it0; it<it1; ++it){
    if (it+1 < it1) STAGE(buf^1, it+1);
    #pragma unroll
    for (int kc=0; kc<2; ++kc){
      short8v a0 = *(const short8v*)&Ab[buf][((kc*8 + wm*4 + 0)*64 + l)*8];
      short8v a1 = *(const short8v*)&Ab[buf][((kc*8 + wm*4 + 1)*64 + l)*8];
      short8v a2 = *(const short8v*)&Ab[buf][((kc*8 + wm*4 + 2)*64 + l)*8];
      short8v a3 = *(const short8v*)&Ab[buf][((kc*8 + wm*4 + 3)*64 + l)*8];
      short8v b0 = *(const short8v*)&Bb[buf][((kc*4 + wn*2 + 0)*64 + l)*8];
      short8v b1 = *(const short8v*)&Bb[buf][((kc*4 + wn*2 + 1)*64 + l)*8];
      acc[0][0] = __builtin_amdgcn_mfma_f32_16x16x32_bf16(a0, b0, acc[0][0], 0,0,0);
      acc[1][0] = __builtin_amdgcn_mfma_f32_16x16x32_bf16(a1, b0, acc[1][0], 0,0,0);
      acc[2][0] = __builtin_amdgcn_mfma_f32_16x16x32_bf16(a2, b0, acc[2][0], 0,0,0);
      acc[3][0] = __builtin_amdgcn_mfma_f32_16x16x32_bf16(a3, b0, acc[3][0], 0,0,0);
      acc[0][1] = __builtin_amdgcn_mfma_f32_16x16x32_bf16(a0, b1, acc[0][1], 0,0,0);
      acc[1][1] = __builtin_amdgcn_mfma_f32_16x16x32_bf16(a1, b1, acc[1][1], 0,0,0);
      acc[2][1] = __builtin_amdgcn_mfma_f32_16x16x32_bf16(a2, b1, acc[2][1], 0,0,0);
      acc[3][1] = __builtin_amdgcn_mfma_f32_16x16x32_bf16(a3, b1, acc[3][1], 0,0,0);
    }
    __syncthreads();
    buf ^= 1;
  }

  const int r0 = (l>>4)*4, cl = l&15;
  float* ob = outp + (size_t)(cot*128 + wm*64)*N + pos0 + wn*32 + cl;
  #pragma unroll
  for (int mf=0; mf<4; ++mf)
    #pragma unroll
    for (int nf=0; nf<2; ++nf){
      float* op = ob + (size_t)(mf*16 + r0)*N + nf*16;
      #pragma unroll
      for (int i=0;i<4;++i) op[(size_t)i*N] = acc[mf][nf][i];
    }
}

// 3b) combine conv K-partials: outputs += PARTK
__global__ void k_combine(float* __restrict__ ws){
  int i = blockIdx.x*256 + threadIdx.x;          // 2,752,512 exact
  ws[OFF_SF8 + i] += ws[OFF_PARTK + i];
}

// ---------------------------------------------------------------------------
// 3c) fbpack: transpose conv outputs f32 [ch][P] -> FB bf16 [row=pos][256ch]
__global__ __launch_bounds__(256) void k_fbpack(float* __restrict__ ws){
  int bx = blockIdx.x;
  int tsr = bx/84, r = bx%84;
  int s, b, chunk;
  if (r < 4)       { s=0; b=r;        chunk=0; }
  else if (r < 20) { s=1; int q=r-4;  b=q>>2; chunk=q&3; }
  else             { s=2; int q=r-20; b=q>>4; chunk=q&15; }
  int P = SSARR[s]*SSARR[s];
  size_t fbase = (s==0)? (tsr?OFF_TF8 :OFF_SF8)
               : (s==1)? (tsr?OFF_TF16:OFF_SF16)
                       : (tsr?OFF_TF32:OFF_SF32);
  const float* src = ws + fbase + (size_t)b*256*P;
  int pos0 = chunk*64;
  const int t = threadIdx.x;
  __shared__ float tile[64][260];
  for (int i=0;i<64;i++){
    int idx = t + i*256; int ch = idx>>6, pl = idx&63;
    tile[pl][ch] = src[(size_t)ch*P + pos0 + pl];
  }
  __syncthreads();
  int rowbase = tsr*5376 + (s==0?0: s==1?256:1280) + b*P + pos0;
  unsigned short* FB = (unsigned short*)(ws + OFF_FB);
  for (int i=0;i<64;i++){
    int idx = t + i*256; int pl = idx>>8, ch = idx&255;
    FB[(size_t)(rowbase+pl)*256 + ch] = f2bf(tile[pl][ch]);
  }
}

// 4) invnorm v3: 16 lanes per row, shfl reduce. 672 blocks.
__global__ void k_invnorm(float* __restrict__ ws){
  int gid = blockIdx.x*256 + threadIdx.x;        // 172,032 exact
  int row = gid >> 4, sub = gid & 15;
  const unsigned short* fb = (const unsigned short*)(ws + OFF_FB)
                           + (size_t)row*256 + sub*16;
  float s = 0.f;
  #pragma unroll
  for (int i=0;i<2;i++){
    short8v v = *(const short8v*)(fb + i*8);
    #pragma unroll
    for (int j=0;j<8;j++){
      float f = bf2f(((unsigned short*)&v)[j]);
      s = fmaf(f, f, s);
    }
  }
  #pragma unroll
  for (int m=1; m<16; m<<=1) s += __shfl_xor(s, m);
  if (sub == 0){
    int tsr = row/5376, r = row%5376;
    ws[(tsr ? OFF_INVT : OFF_INVS) + r] = 1.f/sqrtf(s);
  }
}

// ---------------------------------------------------------------------------
// 5) corr v2: bf16 MFMA GEMM, 64x64 tiles, K=256, operands direct from FB
__global__ __launch_bounds__(256) void k_corr(float* __restrict__ ws){
  int bx = blockIdx.x;
  int p = (bx>=4)+(bx>=20)+(bx>=84)+(bx>=100)+(bx>=164)+(bx>=420)+(bx>=484)+(bx>=740);
  int si = p/3, ti = p%3;
  int M = SSARR[si]*SSARR[si], N = SSARR[ti]*SSARR[ti];
  int ntN = N >> 6;
  int rem = bx - PAIR_START[p];
  int b = rem & 3; rem >>= 2;
  int nt = rem % ntN, mt = rem / ntN;
  int m0 = mt*64, n0 = nt*64;
  const unsigned short* FB = (const unsigned short*)(ws + OFF_FB);
  const unsigned short* Ap = FB + (size_t)((si==0?0: si==1?256:1280) + b*M + m0)*256;
  const unsigned short* Bp = FB + (size_t)(5376 + (ti==0?0: ti==1?256:1280) + b*N + n0)*256;
  const int t = threadIdx.x, l = t&63, w = t>>6, wm = w&1, wn = w>>1;
  const int mrow = wm*32 + (l&15), ncol = wn*32 + (l&15);
  f32x4 acc[2][2];
  #pragma unroll
  for (int i=0;i<2;i++)
    #pragma unroll
    for (int j=0;j<2;j++) acc[i][j] = (f32x4){0.f,0.f,0.f,0.f};
  #pragma unroll
  for (int ksp=0; ksp<8; ++ksp){
    const int ko = ksp*32 + ((l>>4)&3)*8;
    short8v a0 = *(const short8v*)(Ap + (size_t) mrow     *256 + ko);
    short8v a1 = *(const short8v*)(Ap + (size_t)(mrow+16) *256 + ko);
    short8v b0 = *(const short8v*)(Bp + (size_t) ncol     *256 + ko);
    short8v b1 = *(const short8v*)(Bp + (size_t)(ncol+16) *256 + ko);
    acc[0][0] = __builtin_amdgcn_mfma_f32_16x16x32_bf16(a0, b0, acc[0][0], 0,0,0);
    acc[1][0] = __builtin_amdgcn_mfma_f32_16x16x32_bf16(a1, b0, acc[1][0], 0,0,0);
    acc[0][1] = __builtin_amdgcn_mfma_f32_16x16x32_bf16(a0, b1, acc[0][1], 0,0,0);
    acc[1][1] = __builtin_amdgcn_mfma_f32_16x16x32_bf16(a1, b1, acc[1][1], 0,0,0);
  }
  const float* iS = ws + OFF_INVS + (si==0?0: si==1?256:1280) + (size_t)b*M;
  const float* iT = ws + OFF_INVT + (ti==0?0: ti==1?256:1280) + (size_t)b*N;
  float* C = ws + PAIR_OFF[p] + (size_t)b*M*N;
  const int r0 = (l>>4)*4, cl = l&15;
  #pragma unroll
  for (int mf=0; mf<2; ++mf)
    #pragma unroll
    for (int nf=0; nf<2; ++nf)
      #pragma unroll
      for (int i=0;i<4;++i){
        int m = m0 + wm*32 + mf*16 + r0 + i;
        int n = n0 + wn*32 + nf*16 + cl;
        C[(size_t)m*N + n] = acc[mf][nf][i]*iS[m]*iT[n];
      }
}

// ---------------------------------------------------------------------------
DEVFN void cw_coord(int i, int n, int OH, int& i0, int& i1, float& f){
  float c = (float)(i*(n-1))/(float)(OH-1);
  int a = (int)c; if (a > n-1) a = n-1;
  i0 = a; i1 = (a+1 < n) ? a+1 : n-1; f = c - (float)a;
}

// 6) interp_pairs v2: block = (p,b,oy,ox); stage 4 corner (y,x) planes in LDS
__global__ __launch_bounds__(256) void k_interp_pairs(float* __restrict__ ws){
  int bx = blockIdx.x;
  int p = bx >> 10;
  int bl = bx & 1023;                    // [b:2][oy:4][ox:4]
  int b = bl >> 8, oy = (bl >> 4) & 15, ox = bl & 15;
  int si = p/3, ti = p%3;
  int h1 = SSARR[si], t1 = SSARR[ti], t12 = t1*t1;
  int y0,y1,x0,x1; float fy,fx;
  cw_coord(oy,h1,16,y0,y1,fy); cw_coord(ox,h1,16,x0,x1,fx);
  const float* in = ws + PAIR_OFF[p] + (size_t)b*h1*h1*t12;
  __shared__ float sPl[4][1024];
  const int t = threadIdx.x;
  {
    const float* pl0 = in + (size_t)(y0*h1+x0)*t12;
    const float* pl1 = in + (size_t)(y0*h1+x1)*t12;
    const float* pl2 = in + (size_t)(y1*h1+x0)*t12;
    const float* pl3 = in + (size_t)(y1*h1+x1)*t12;
    for (int i=t; i<t12; i+=256){
      sPl[0][i] = pl0[i]; sPl[1][i] = pl1[i];
      sPl[2][i] = pl2[i]; sPl[3][i] = pl3[i];
    }
  }
  __syncthreads();
  int px = t & 15, py = t >> 4;
  int u0,u1,v0,v1; float fu,fv;
  cw_coord(py,t1,16,u0,u1,fu); cw_coord(px,t1,16,v0,v1,fv);
  float wY[2]={1.f-fy,fy}, wX[2]={1.f-fx,fx};
  float wU[2]={1.f-fu,fu}, wV[2]={1.f-fv,fv};
  int us[2]={u0,u1}, vs[2]={v0,v1};
  float s = 0.f;
  #pragma unroll
  for (int qa=0; qa<2; qa++)
    #pragma unroll
    for (int qc=0; qc<2; qc++){
      float wyx = wY[qa]*wX[qc];
      const float* base = sPl[qa*2+qc];
      #pragma unroll
      for (int qu=0; qu<2; qu++)
        #pragma unroll
        for (int qv=0; qv<2; qv++)
          s += wyx*wU[qu]*wV[qv]*base[us[qu]*t1 + vs[qv]];
    }
  ws[OFF_CORR6 + ((size_t)b*9 + p)*65536 + ((size_t)(oy*16+ox)<<8) + t] = fmaxf(s, 0.f);
}

// ---------------------------------------------------------------------------
// 6b) k_cl v2: coalesced transpose via LDS (R14)
__global__ __launch_bounds__(256) void k_cl(float* __restrict__ ws){
  int bx = blockIdx.x;                      // 1024 = b*256 + yx
  int b = bx >> 8, yx = bx & 255;
  const int t = threadIdx.x;
  __shared__ __align__(16) unsigned short tile[10080];   // [yp20][xp21][pr24]
  for (int i=t; i<1260; i+=256)
    *reinterpret_cast<f32x4*>((float*)&tile[i*8]) = (f32x4){0.f,0.f,0.f,0.f};
  __syncthreads();
  const float* c6 = ws + OFF_CORR6 + ((size_t)b*9 << 16) + ((size_t)yx << 8);
  const int qy = t >> 4, qx = t & 15;
  const int wo = ((2+qy)*21 + 2+qx)*24;
  #pragma unroll
  for (int pr=0; pr<9; ++pr)
    tile[wo + pr] = f2bf(c6[((size_t)pr << 16) + t]);
  __syncthreads();
  unsigned short* o = (unsigned short*)(ws + OFF_CL) + (size_t)bx*10080;
  for (int i=t; i<1260; i+=256)
    *reinterpret_cast<f32x4*>((float*)&o[i*8]) =
      *reinterpret_cast<const f32x4*>((const float*)&tile[i*8]);
}

// ---------------------------------------------------------------------------
// 7) chm6d v7: bf16 MFMA implicit GEMM + fused sigmoid/max epilogue (R11)
__global__ __launch_bounds__(256) void k_chm6d(float* __restrict__ ws){
  int id = (blockIdx.x & 7)*128 + (blockIdx.x >> 3);   // XCD swizzle, bijective
  const int b = id >> 8, sy = (id >> 4) & 15, sx = id & 15;
  const int t = threadIdx.x, l = t & 63, w = t >> 6;
  const int x = l & 15, h = (l >> 4) & 1, e2 = (l >> 4) >> 1;
  const unsigned short* CLu = (const unsigned short*)(ws + OFF_CL);
  const unsigned short* WAu = (const unsigned short*)(ws + OFF_WA);
  __shared__ __align__(16) unsigned short tile[2][10080];   // 40,320 B

  f32x4 acc[4];
  #pragma unroll
  for (int i=0;i<4;i++) acc[i] = (f32x4){0.f,0.f,0.f,0.f};

  auto STAGE = [&](int buf, int YX){
    const unsigned short* src = CLu + (size_t)(b*256 + YX)*10080;
    #pragma unroll
    for (int j=0;j<5;++j){
      int ch = t + j*256;
      if (ch < 1260) gl_lds16(src + (size_t)ch*8, &tile[buf][ch*8]);
    }
  };

  const int xb0 = (x + e2)*24 + 8*h;

  int i0 = 0;
  for (; i0 < 25; ++i0){
    int Y = sy + i0/5 - 2, X = sx + i0%5 - 2;
    if (Y>=0 && Y<=15 && X>=0 && X<=15) break;
  }
  {
    int Y = sy + i0/5 - 2, X = sx + i0%5 - 2;
    STAGE(0, Y*16 + X);
  }
  __syncthreads();
  int buf = 0, i = i0;
  #pragma unroll 1
  while (i < 25){
    int nx = i + 1;
    for (; nx < 25; ++nx){
      int Y = sy + nx/5 - 2, X = sx + nx%5 - 2;
      if (Y>=0 && Y<=15 && X>=0 && X<=15) break;
    }
    if (nx < 25){
      int Y = sy + nx/5 - 2, X = sx + nx%5 - 2;
      STAGE(buf^1, Y*16 + X);
    }
    {
      const unsigned short* wa = WAu + (size_t)i*5*3*512;   // [d][kc][lane][8]
      short8v afr[5][3];
      #pragma unroll
      for (int d=0; d<5; ++d)
        #pragma unroll
        for (int kc=0; kc<3; ++kc)
          afr[d][kc] = *(const short8v*)&wa[((d*3 + kc)*64 + l)*8];
      const unsigned short* tb = &tile[buf][0];
      #pragma unroll
      for (int rl=0; rl<8; ++rl){
        const int row = (w*4 + rl)*504;
        short8v bf0 = *(const short8v*)&tb[row + xb0];
        short8v bf1 = *(const short8v*)&tb[row + xb0 + 48];
        short8v bf2 = *(const short8v*)&tb[row + xb0 + 96];
        #pragma unroll
        for (int y=0; y<4; ++y){
          if (y <= rl && rl - y <= 4){
            const int d = rl - y;
            acc[y] = __builtin_amdgcn_mfma_f32_16x16x32_bf16(afr[d][0], bf0, acc[y], 0,0,0);
            acc[y] = __builtin_amdgcn_mfma_f32_16x16x32_bf16(afr[d][1], bf1, acc[y], 0,0,0);
            acc[y] = __builtin_amdgcn_mfma_f32_16x16x32_bf16(afr[d][2], bf2, acc[y], 0,0,0);
          }
        }
      }
    }
    __syncthreads();
    buf ^= 1; i = nx;
  }

  const int g = l >> 4;
  float* maxed = ws + OFF_MAXED + (size_t)b*65536 + (size_t)(sy*16+sx)*256;
  #pragma unroll
  for (int y=0; y<4; ++y){
    float lm;
    if (g < 2)      lm = fmaxf(fmaxf(acc[y][0], acc[y][1]), fmaxf(acc[y][2], acc[y][3]));
    else if (g==2)  lm = acc[y][0];
    else            lm = -1e30f;
    lm = fmaxf(lm, __shfl_xor(lm, 16));
    lm = fmaxf(lm, __shfl_xor(lm, 32));
    if (l < 16)
      maxed[(w*4 + y)*16 + x] = 1.f/(1.f + expf(-lm));
  }
}

// ---------------------------------------------------------------------------
// 8) interpolate4d 16^4 -> 32^4
__global__ void k_interp32(float* __restrict__ ws){
  int id = blockIdx.x*256 + threadIdx.x;
  int px = id & 31, py = (id>>5)&31, ox = (id>>10)&31, oy = (id>>15)&31, b = id>>20;
  int y0,y1,x0,x1,u0,u1,v0,v1; float fy,fx,fu,fv;
  cw_coord(oy,16,32,y0,y1,fy); cw_coord(ox,16,32,x0,x1,fx);
  cw_coord(py,16,32,u0,u1,fu); cw_coord(px,16,32,v0,v1,fv);
  const float* in = ws + OFF_MAXED + (size_t)b*65536;
  int ys[2]={y0,y1}, xs[2]={x0,x1}, us[2]={u0,u1}, vs[2]={v0,v1};
  float wy[2]={1.f-fy,fy}, wx[2]={1.f-fx,fx}, wu[2]={1.f-fu,fu}, wv[2]={1.f-fv,fv};
  float s = 0.f;
  #pragma unroll
  for (int ia=0; ia<2; ia++)
    #pragma unroll
    for (int ic=0; ic<2; ic++){
      float wyx = wy[ia]*wx[ic];
      const float* base = in + ((size_t)ys[ia]*16 + xs[ic])*256;
      #pragma unroll
      for (int id_=0; id_<2; id_++)
        #pragma unroll
        for (int ie=0; ie<2; ie++)
          s += wyx*wu[id_]*wv[ie]*base[(size_t)us[id_]*16 + vs[ie]];
    }
  ws[OFF_INT32 + id] = s;
}

// ---------------------------------------------------------------------------
// 9) fast4d v7: bf16 MFMA implicit GEMM. Block = (b, syb8, sxb8, yh4);
//    M=16 so=(soy,sox), N=16 x (xg 2), K=(e5, pl=8x8 plane window) per d.
//    LDS tile T[ry12][x'36][pl64] bf16 (channels-last, zero-padded halo).
//    Fused bias+softplus+rowmax partials -> SMAXP[yh].
__global__ __launch_bounds__(256) void k_fast4d(float* __restrict__ ws,
                                                const float* __restrict__ b4,
                                                float* __restrict__ out){
  int id = (blockIdx.x & 7)*128 + (blockIdx.x >> 3);   // bijective 1024
  const int b = id >> 8, rem = id & 255;
  const int syb = rem >> 5, sxb = (rem >> 2) & 7, yh = rem & 3;
  const int t = threadIdx.x, l = t & 63, w = t >> 6;
  __shared__ __align__(16) unsigned short T[27648];    // 55,296 B
  __shared__ float red[4][16];
  for (int i=t; i<3456; i+=256)
    *reinterpret_cast<f32x4*>((float*)&T[i*8]) = (f32x4){0.f,0.f,0.f,0.f};
  __syncthreads();
  const float* I = ws + OFF_INT32 + (size_t)b*1048576;
  #pragma unroll 4
  for (int j=0; j<48; ++j){
    int idx2 = j*256 + t;
    int xo = idx2 & 15, pl = (idx2>>4) & 63, ry = idx2 >> 10;
    int pya = syb*4 + (pl>>3) - 2;
    int pxa = sxb*4 + (pl&7) - 2;
    int rya = yh*8 + ry - 2;
    if (pya>=0 && pya<32 && pxa>=0 && pxa<32 && rya>=0 && rya<32){
      float2 v = *reinterpret_cast<const float2*>(
          I + (size_t)(pya*32+pxa)*1024 + rya*32 + xo*2);
      int base = (ry*36 + xo*2 + 2)*64 + pl;
      T[base]      = f2bf(v.x);
      T[base + 64] = f2bf(v.y);
    }
  }
  __syncthreads();
  const unsigned short* WA4 = (const unsigned short*)(ws + OFF_WA4);
  f32x4 acc[2][2];
  #pragma unroll
  for (int i=0;i<2;i++)
    #pragma unroll
    for (int j=0;j<2;j++) acc[i][j] = (f32x4){0.f,0.f,0.f,0.f};
  const unsigned short* Tl = T + (l&15)*64 + (l>>4)*8 + w*2*2304;
  #pragma unroll 1
  for (int d=0; d<5; ++d){
    short8v afr[10];
    #pragma unroll
    for (int kc=0; kc<10; ++kc)
      afr[kc] = *(const short8v*)&WA4[((size_t)(d*10 + kc)*64 + l)*8];
    #pragma unroll
    for (int y2=0; y2<2; ++y2){
      const unsigned short* Tr = Tl + (y2 + d)*2304;
      #pragma unroll
      for (int xg=0; xg<2; ++xg){
        const unsigned short* Tx = Tr + xg*1024;
        #pragma unroll
        for (int kc=0; kc<10; ++kc){
          short8v bf = *(const short8v*)&Tx[(kc>>1)*64 + (kc&1)*32];
          acc[y2][xg] = __builtin_amdgcn_mfma_f32_16x16x32_bf16(afr[kc], bf, acc[y2][xg], 0,0,0);
        }
      }
    }
  }
  const float bias = b4[0];
  float rm[4] = {-1e30f,-1e30f,-1e30f,-1e30f};
  #pragma unroll
  for (int y2=0; y2<2; ++y2)
    #pragma unroll
    for (int xg=0; xg<2; ++xg)
      #pragma unroll
      for (int i=0; i<4; ++i){
        int so = (l>>4)*4 + i;
        float xv = acc[y2][xg][i] + bias;
        float sp = fmaxf(xv,0.f) + log1pf(expf(-fabsf(xv)));
        int row = (syb*4 + (so>>2))*32 + sxb*4 + (so&3);
        int col = (yh*8 + w*2 + y2)*32 + xg*16 + (l&15);
        out[((size_t)b*1024 + row)*1024 + col] = sp;
        rm[i] = fmaxf(rm[i], sp);
      }
  #pragma unroll
  for (int m=1; m<16; m<<=1)
    #pragma unroll
    for (int i=0;i<4;++i) rm[i] = fmaxf(rm[i], __shfl_xor(rm[i], m));
  if ((l & 15) == 0){
    #pragma unroll
    for (int i=0;i<4;++i) red[w][(l>>4)*4 + i] = rm[i];
  }
  __syncthreads();
  if (t < 16){
    float m = fmaxf(fmaxf(red[0][t], red[1][t]), fmaxf(red[2][t], red[3][t]));
    int row = (syb*4 + (t>>2))*32 + sxb*4 + (t&3);
    ws[OFF_SMAXP + (size_t)yh*4096 + (size_t)b*1024 + row] = m;
  }
}

// ---------------------------------------------------------------------------
// 10-12) mutual_nn_filter
__global__ void k_colmax_p(const float* __restrict__ cm, float* __restrict__ ws){
  int b = blockIdx.x >> 7, rg = (blockIdx.x >> 2) & 31, cg = blockIdx.x & 3;
  int c = cg*256 + threadIdx.x;
  const float* base = cm + (size_t)b*1048576 + (size_t)rg*32768 + c;
  float m = -1e30f;
  #pragma unroll 4
  for (int r=0; r<32; r++) m = fmaxf(m, base[(size_t)r*1024]);
  ws[OFF_CMAXP + (size_t)(b*32+rg)*1024 + c] = m;
}

__global__ void k_colmax_r(float* __restrict__ ws){
  int id = blockIdx.x*256 + threadIdx.x;         // 4096
  int b = id >> 10, c = id & 1023;
  float m = -1e30f;
  #pragma unroll
  for (int rg=0; rg<32; rg++)
    m = fmaxf(m, ws[OFF_CMAXP + (size_t)(b*32+rg)*1024 + c]);
  ws[OFF_TMAX + id] = m;
}

__global__ void k_mutual(float* __restrict__ cm, const float* __restrict__ ws){
  int id = blockIdx.x*256 + threadIdx.x;
  int b = id >> 20, r = (id>>10)&1023, c = id&1023;
  float v  = cm[id];
  size_t si = (size_t)(b<<10) + r;
  float sm = fmaxf(fmaxf(ws[OFF_SMAXP + si],        ws[OFF_SMAXP + 4096 + si]),
                   fmaxf(ws[OFF_SMAXP + 8192 + si], ws[OFF_SMAXP + 12288 + si]));
  float tm = ws[OFF_TMAX + (b<<10) + c];
  sm = (sm==0.f) ? 1e-30f : sm;
  tm = (tm==0.f) ? 1e-30f : tm;
  cm[id] = v * (v/sm) * (v/tm);
}

// ---------------------------------------------------------------------------
extern "C" void kernel_launch(void* const* d_in, const int* in_sizes, int n_in,
                              void* d_out, int out_size, void* d_ws, size_t ws_size,
                              hipStream_t stream){
  const float* src = (const float*)d_in[0];
  const float* trg = (const float*)d_in[1];
  const float* w0  = (const float*)d_in[2];
  const float* w1  = (const float*)d_in[3];
  const float* w2  = (const float*)d_in[4];
  const float* k6  = (const float*)d_in[5];
  const float* k4  = (const float*)d_in[6];
  const float* b4  = (const float*)d_in[7];
  float* ws  = (float*)d_ws;    // needs WS_FLOATS*4 = ~72.6 MB
  float* out = (float*)d_out;
  (void)in_sizes; (void)n_in; (void)out_size; (void)ws_size;

  k_wpack       <<<768,   256, 0, stream>>>(w0, w1, w2, ws);
  k_wa          <<<94,    256, 0, stream>>>(k6, ws);
  k_wa4         <<<13,    256, 0, stream>>>(k4, ws);
  k_inpack      <<<512,   256, 0, stream>>>(src, trg, ws);
  k_conv_mfma   <<<672,   256, 0, stream>>>(ws);
  k_combine     <<<10752, 256, 0, stream>>>(ws);
  k_fbpack      <<<168,   256, 0, stream>>>(ws);
  k_invnorm     <<<672,   256, 0, stream>>>(ws);
  k_corr        <<<1764,  256, 0, stream>>>(ws);
  k_interp_pairs<<<9216,  256, 0, stream>>>(ws);
  k_cl          <<<1024,  256, 0, stream>>>(ws);
  k_chm6d       <<<1024,  256, 0, stream>>>(ws);
  k_interp32    <<<16384, 256, 0, stream>>>(ws);
  k_fast4d      <<<1024,  256, 0, stream>>>(ws, b4, out);
  k_colmax_p    <<<512,   256, 0, stream>>>(out, ws);
  k_colmax_r    <<<16,    256, 0, stream>>>(ws);
  k_mutual      <<<16384, 256, 0, stream>>>(out, ws);
}

// Round 20
// 371.069 us; speedup vs baseline: 1.2019x; 1.0162x over previous
//
#include <hip/hip_runtime.h>
#include <cstdint>
#include <cstddef>

// ============================================================================
// CHMLearner forward. R20: R19's conv locality swizzle + fused fbpack, with
// FB moved to a FRESH region at workspace end (R19's FB2 aliased corr pair 8
// output -> race). Rest identical to R18.
// ============================================================================

#define DEVFN __device__ __forceinline__

typedef __attribute__((ext_vector_type(8))) short short8v;
typedef __attribute__((ext_vector_type(4))) float f32x4;
typedef unsigned int u32;

DEVFN void gl_lds16(const void* g, void* l){
  __builtin_amdgcn_global_load_lds(
      (const __attribute__((address_space(1))) u32*)g,
      (__attribute__((address_space(3))) u32*)l, 16, 0, 0);
}

// workspace layout (float units). Total ~78.1 MB
constexpr size_t OFF_WB    = 0;           // bf16 packed conv weights
constexpr size_t OFF_P8    = 3538944;     // bf16 padded ch-last features
constexpr size_t OFF_P16   = 3948544;
constexpr size_t OFF_P32   = 5275648;
constexpr size_t OFF_SF8   = 10010624;    // conv outputs f32 [b][256][S*S]
constexpr size_t OFF_TF8   = 10076160;
constexpr size_t OFF_SF16  = 10141696;
constexpr size_t OFF_TF16  = 10403840;
constexpr size_t OFF_SF32  = 10665984;
constexpr size_t OFF_TF32  = 11714560;
constexpr size_t OFF_INVS  = 12763136;
constexpr size_t OFF_INVT  = 12768512;
constexpr size_t OFF_TMAX  = 12777984;    // 4096 colmax
constexpr size_t OFF_CORR6 = 12782080;    // [4][9][16^4] f32
constexpr size_t OFF_CMAXP = OFF_CORR6 + 2359296 + 128;   // 131072 colmax partials
constexpr size_t OFF_WA    = OFF_CMAXP + 131072;          // 192,000 bf16
constexpr size_t OFF_PARTK = OFF_WA + 96128;              // 2,752,512 conv K-partials
constexpr size_t OFF_SMAXP = OFF_PARTK + 2752512;         // [4yh][4b][1024] rowmax
constexpr size_t OFF_WA4   = OFF_SMAXP + 16384;           // 25,600 bf16
constexpr size_t OFF_FB3   = OFF_WA4 + 12800;             // bf16 [10752][256] fresh
constexpr size_t WS_FLOATS = OFF_FB3 + 1376256;

// aliases into dead regions:
__device__ constexpr size_t PAIR_OFF[9] = {   // raw per-pair corr [4][ss^2][ts^2]
  OFF_WB + 0,       OFF_WB + 16384,   OFF_WB + 81920,
  OFF_WB + 344064,  OFF_WB + 409600,  OFF_WB + 671744,
  OFF_WB + 1720320, OFF_WB + 1982464, OFF_WB + 3031040 };  // pair8 ends 7,225,344
constexpr size_t OFF_CL    = 0;            // bf16 [4][256][20][21][24]
constexpr size_t OFF_MAXED = 9437184;      // [4][16^4] f32
constexpr size_t OFF_INT32 = 262144;       // [4][32^4] f32 (CL dead by interp32)

__device__ constexpr int SSARR[3] = {8, 16, 32};
__device__ constexpr int PAIR_START[9] = {0,4,20,84,100,164,420,484,740}; // 1764

DEVFN unsigned short f2bf(float f){
  unsigned int u = __float_as_uint(f);
  return (unsigned short)((u + 0x7fffu + ((u >> 16) & 1u)) >> 16);
}
DEVFN float bf2f(unsigned short u){
  return __uint_as_float(((unsigned int)u) << 16);
}

// ---------------------------------------------------------------------------
// 1) wpack v2: coalesced via LDS transpose (R13)
__global__ __launch_bounds__(256) void k_wpack(const float* __restrict__ w0,
                                               const float* __restrict__ w1,
                                               const float* __restrict__ w2,
                                               float* __restrict__ wsf){
  int bx = blockIdx.x;
  int scale = bx >> 8, cg = (bx >> 4) & 15, ig = bx & 15;
  const float* w = (scale==0) ? w0 : (scale==1 ? w1 : w2);
  const int t = threadIdx.x;
  __shared__ float sW[16*580];
  const float* src = w + (size_t)cg*16*9216 + (size_t)ig*576;
  for (int i=t; i<9216; i+=256){
    int co = i/576, r = i%576;
    sW[co*580 + r] = src[(size_t)co*9216 + r];
  }
  __syncthreads();
  unsigned short* ob = (unsigned short*)(wsf + OFF_WB) + (size_t)scale*2359296;
  for (int f=t; f<1152; f+=256){
    int tap = f/128, rem = f%128, kcl = rem>>6, l = rem&63;
    int kc = ig*2 + kcl;
    int co = l & 15;
    int ciL = kcl*32 + ((l>>4)&3)*8;
    unsigned short* o = ob + ((size_t)tap*32768 + (size_t)kc*1024 + (size_t)cg*64 + l)*8;
    #pragma unroll
    for (int i=0;i<8;i++)
      o[i] = f2bf(sW[co*580 + (ciL+i)*9 + tap]);
  }
}

// 1b) pack chm6d weights into MFMA A-fragment order
__global__ void k_wa(const float* __restrict__ k6, float* __restrict__ wsf){
  int gid = blockIdx.x*256 + threadIdx.x;        // 24,000
  if (gid >= 24000) return;
  int tap = gid / 192, rem = gid % 192;
  int kc = rem / 64, l = rem % 64;
  int d = tap % 5, ac = tap / 5, a = ac / 5, c = ac % 5;
  int so = l & 15, k8 = (l >> 4) * 8;
  unsigned short* o = (unsigned short*)(wsf + OFF_WA) + (size_t)gid*8;
  #pragma unroll
  for (int i=0;i<8;i++){
    int kg = kc*32 + k8 + i;
    int e = kg >> 4, pr = kg & 15;
    float v = 0.f;
    if (so < 9 && pr < 9 && e < 5){
      int pi = pr/3, pj = pr%3, sio = so/3, sjo = so%3;
      int ki = pi - sio + 1, kj = pj - sjo + 1;
      if (ki>=0 && ki<=2 && kj>=0 && kj<=2)
        v = k6[(((((ki*3+kj)*5 + a)*5 + c)*5 + d)*5) + e];
    }
    o[i] = f2bf(v);
  }
}

// 1c) pack fast4d weights: WA4[d][kc][lane][8]
__global__ void k_wa4(const float* __restrict__ k4, float* __restrict__ wsf){
  int gid = blockIdx.x*256 + threadIdx.x;        // 3200
  if (gid >= 3200) return;
  int d = gid / 640, rem = gid % 640;
  int kc = rem / 64, l = rem % 64;
  int so = l & 15, soy = so >> 2, sox = so & 3;
  int e = kc >> 1;
  int pyw = 4*(kc & 1) + (l >> 4);
  unsigned short* o = (unsigned short*)(wsf + OFF_WA4) + (size_t)gid*8;
  #pragma unroll
  for (int i=0;i<8;i++){
    int a = pyw - soy, c = i - sox;
    float v = 0.f;
    if (a>=0 && a<=4 && c>=0 && c<=4)
      v = k4[((a*5 + c)*5 + d)*5 + e];
    o[i] = f2bf(v);
  }
}

// ---------------------------------------------------------------------------
// 2) inpack: stage 16 channels' 16x16 planes in LDS; emit all 3 scales
__global__ __launch_bounds__(256) void k_inpack(const float* __restrict__ src,
                                                const float* __restrict__ trg,
                                                float* __restrict__ wsf){
  int bt = blockIdx.x >> 6, cg = blockIdx.x & 63;
  int chbase = cg*16;
  int t = threadIdx.x;
  __shared__ float sIn[16][257];
  const float* gin = ((bt>=4)? trg : src) + ((size_t)(bt&3)*1024 + chbase)*256;
  #pragma unroll
  for (int i=0;i<16;i++){
    int idx = t + i*256; int ch = idx>>8, pos = idx&255;
    sIn[ch][pos] = gin[(size_t)ch*256 + pos];
  }
  __syncthreads();
  int ch = t & 15, pw = t >> 4;
  #pragma unroll 1
  for (int s=0; s<3; s++){
    int S = SSARR[s], Sp = S+2, Sp2 = Sp*Sp;
    size_t poff = (s==0)?OFF_P8 : (s==1)?OFF_P16 : OFF_P32;
    unsigned short* o = (unsigned short*)(wsf + poff) + (size_t)bt*Sp2*1024 + chbase + ch;
    float rs = 15.f/(float)(S-1);
    for (int i = pw; i < Sp2; i += 16){
      int py = i / Sp, px = i % Sp;
      float v = 0.f;
      if (py>0 && py<Sp-1 && px>0 && px<Sp-1){
        float cy = (float)(py-1)*rs, cx = (float)(px-1)*rs;
        int y0 = (int)cy; if (y0>15) y0=15; int y1 = (y0+1<16)?y0+1:15; float fy = cy-(float)y0;
        int x0 = (int)cx; if (x0>15) x0=15; int x1 = (x0+1<16)?x0+1:15; float fx = cx-(float)x0;
        v = (1.f-fy)*((1.f-fx)*sIn[ch][y0*16+x0] + fx*sIn[ch][y0*16+x1])
          +       fy*((1.f-fx)*sIn[ch][y1*16+x0] + fx*sIn[ch][y1*16+x1]);
      }
      o[(size_t)i*1024] = f2bf(v);
    }
  }
}

// ---------------------------------------------------------------------------
// 3) conv3x3 bf16 MFMA GEMM, K-split x2, locality swizzle (R19, verified
//    bijective): scale-2: XCD = (bt*2+cot) mod 8 owns all 32 (post,ks).
__global__ __launch_bounds__(256) void k_conv_mfma(float* __restrict__ wsf){
  int bxid = blockIdx.x;
  int scale, bt, cot, post, ks, S, lgS;
  if (bxid < 512){
    int xcd = bxid & 7, j2 = bxid >> 3;
    int g = (j2 >> 5)*8 + xcd;
    int j = j2 & 31;
    scale = 2; S = 32; lgS = 5;
    bt = g >> 1; cot = g & 1; post = j >> 1; ks = j & 1;
  } else {
    int r = bxid - 512;
    ks = r & 1; int bx = 256 + (r >> 1);
    if (bx < 320){ int q=bx-256; scale=1; S=16; lgS=4; bt=q>>3; cot=(q>>2)&1; post=q&3; }
    else         { int q=bx-320; scale=0; S=8;  lgS=3; bt=q>>1; cot=q&1; post=0; }
  }
  const int Sp = S+2, N = S*S;
  const unsigned short* WbS = (const unsigned short*)(wsf + OFF_WB) + (size_t)scale*2359296;
  size_t poff = scale==0?OFF_P8: scale==1?OFF_P16:OFF_P32;
  const unsigned short* Pb = (const unsigned short*)(wsf + poff) + (size_t)bt*Sp*Sp*1024;
  size_t obase = (scale==2) ? (bt>=4?OFF_TF32:OFF_SF32)
               : (scale==1) ? (bt>=4?OFF_TF16:OFF_SF16)
                            : (bt>=4?OFF_TF8 :OFF_SF8);
  if (ks) obase += OFF_PARTK - OFF_SF8;
  float* outp = wsf + obase + (size_t)(bt&3)*256*N;

  const int t = threadIdx.x, l = t&63, w = t>>6, wm = w&1, wn = w>>1;
  const int nc_base = cot*8;
  const int pos0 = post*64;
  const int it0 = ks*72, it1 = it0 + 72;

  __shared__ __align__(16) unsigned short Ab[2][8192];   // 32 KB
  __shared__ __align__(16) unsigned short Bb[2][4096];   // 16 KB

  f32x4 acc[4][2];
  #pragma unroll
  for (int i=0;i<4;i++)
    #pragma unroll
    for (int j=0;j<2;j++) acc[i][j] = (f32x4){0.f,0.f,0.f,0.f};

  auto STAGE = [&](int buf, int it){
    int tap = it>>4, kq = it&15;
    int dy = tap/3, dx = tap - dy*3;
    #pragma unroll
    for (int j=0;j<4;++j){
      int c = w + j*4;
      int kc = c>>3, nc = c&7;
      const unsigned short* src =
        WbS + ((((size_t)tap*32 + kq*2 + kc)*16 + nc_base + nc)*64 + l)*8;
      gl_lds16(src, &Ab[buf][c*512]);
    }
    #pragma unroll
    for (int j=0;j<2;++j){
      int c = w + j*4;
      int kc = c>>2, np = c&3;
      int pos = pos0 + np*16 + (l&15);
      int y = pos>>lgS, x = pos&(S-1);
      int row = (y+dy)*Sp + (x+dx);
      int ci = kq*64 + kc*32 + ((l>>4)<<3);
      gl_lds16(Pb + (size_t)row*1024 + ci, &Bb[buf][c*512]);
    }
  };

  STAGE(0, it0);
  __syncthreads();
  int buf = 0;
  #pragma unroll 1
  for (int it=it0; it<it1; ++it){
    if (it+1 < it1) STAGE(buf^1, it+1);
    #pragma unroll
    for (int kc=0; kc<2; ++kc){
      short8v a0 = *(const short8v*)&Ab[buf][((kc*8 + wm*4 + 0)*64 + l)*8];
      short8v a1 = *(const short8v*)&Ab[buf][((kc*8 + wm*4 + 1)*64 + l)*8];
      short8v a2 = *(const short8v*)&Ab[buf][((kc*8 + wm*4 + 2)*64 + l)*8];
      short8v a3 = *(const short8v*)&Ab[buf][((kc*8 + wm*4 + 3)*64 + l)*8];
      short8v b0 = *(const short8v*)&Bb[buf][((kc*4 + wn*2 + 0)*64 + l)*8];
      short8v b1 = *(const short8v*)&Bb[buf][((kc*4 + wn*2 + 1)*64 + l)*8];
      acc[0][0] = __builtin_amdgcn_mfma_f32_16x16x32_bf16(a0, b0, acc[0][0], 0,0,0);
      acc[1][0] = __builtin_amdgcn_mfma_f32_16x16x32_bf16(a1, b0, acc[1][0], 0,0,0);
      acc[2][0] = __builtin_amdgcn_mfma_f32_16x16x32_bf16(a2, b0, acc[2][0], 0,0,0);
      acc[3][0] = __builtin_amdgcn_mfma_f32_16x16x32_bf16(a3, b0, acc[3][0], 0,0,0);
      acc[0][1] = __builtin_amdgcn_mfma_f32_16x16x32_bf16(a0, b1, acc[0][1], 0,0,0);
      acc[1][1] = __builtin_amdgcn_mfma_f32_16x16x32_bf16(a1, b1, acc[1][1], 0,0,0);
      acc[2][1] = __builtin_amdgcn_mfma_f32_16x16x32_bf16(a2, b1, acc[2][1], 0,0,0);
      acc[3][1] = __builtin_amdgcn_mfma_f32_16x16x32_bf16(a3, b1, acc[3][1], 0,0,0);
    }
    __syncthreads();
    buf ^= 1;
  }

  const int r0 = (l>>4)*4, cl = l&15;
  float* ob = outp + (size_t)(cot*128 + wm*64)*N + pos0 + wn*32 + cl;
  #pragma unroll
  for (int mf=0; mf<4; ++mf)
    #pragma unroll
    for (int nf=0; nf<2; ++nf){
      float* op = ob + (size_t)(mf*16 + r0)*N + nf*16;
      #pragma unroll
      for (int i=0;i<4;++i) op[(size_t)i*N] = acc[mf][nf][i];
    }
}

// ---------------------------------------------------------------------------
// 3c) fbpack v2: combine K-partials + transpose + bf16 -> FB3 [row][256ch]
__global__ __launch_bounds__(256) void k_fbpack(float* __restrict__ ws){
  int bx = blockIdx.x;
  int tsr = bx/84, r = bx%84;
  int s, b, chunk;
  if (r < 4)       { s=0; b=r;        chunk=0; }
  else if (r < 20) { s=1; int q=r-4;  b=q>>2; chunk=q&3; }
  else             { s=2; int q=r-20; b=q>>4; chunk=q&15; }
  int P = SSARR[s]*SSARR[s];
  size_t fbase = (s==0)? (tsr?OFF_TF8 :OFF_SF8)
               : (s==1)? (tsr?OFF_TF16:OFF_SF16)
                       : (tsr?OFF_TF32:OFF_SF32);
  const float* src = ws + fbase + (size_t)b*256*P;
  const float* prt = ws + OFF_PARTK + (fbase - OFF_SF8) + (size_t)b*256*P;
  int pos0 = chunk*64;
  const int t = threadIdx.x;
  __shared__ float tile[64][260];
  for (int i=0;i<64;i++){
    int idx = t + i*256; int ch = idx>>6, pl = idx&63;
    size_t o = (size_t)ch*P + pos0 + pl;
    tile[pl][ch] = src[o] + prt[o];
  }
  __syncthreads();
  int rowbase = tsr*5376 + (s==0?0: s==1?256:1280) + b*P + pos0;
  unsigned short* FB = (unsigned short*)(ws + OFF_FB3);
  for (int i=0;i<64;i++){
    int idx = t + i*256; int pl = idx>>8, ch = idx&255;
    FB[(size_t)(rowbase+pl)*256 + ch] = f2bf(tile[pl][ch]);
  }
}

// 4) invnorm v3: 16 lanes per row, shfl reduce. 672 blocks.
__global__ void k_invnorm(float* __restrict__ ws){
  int gid = blockIdx.x*256 + threadIdx.x;        // 172,032 exact
  int row = gid >> 4, sub = gid & 15;
  const unsigned short* fb = (const unsigned short*)(ws + OFF_FB3)
                           + (size_t)row*256 + sub*16;
  float s = 0.f;
  #pragma unroll
  for (int i=0;i<2;i++){
    short8v v = *(const short8v*)(fb + i*8);
    #pragma unroll
    for (int j=0;j<8;j++){
      float f = bf2f(((unsigned short*)&v)[j]);
      s = fmaf(f, f, s);
    }
  }
  #pragma unroll
  for (int m=1; m<16; m<<=1) s += __shfl_xor(s, m);
  if (sub == 0){
    int tsr = row/5376, r = row%5376;
    ws[(tsr ? OFF_INVT : OFF_INVS) + r] = 1.f/sqrtf(s);
  }
}

// ---------------------------------------------------------------------------
// 5) corr v2: bf16 MFMA GEMM, 64x64 tiles, K=256, operands direct from FB3
__global__ __launch_bounds__(256) void k_corr(float* __restrict__ ws){
  int bx = blockIdx.x;
  int p = (bx>=4)+(bx>=20)+(bx>=84)+(bx>=100)+(bx>=164)+(bx>=420)+(bx>=484)+(bx>=740);
  int si = p/3, ti = p%3;
  int M = SSARR[si]*SSARR[si], N = SSARR[ti]*SSARR[ti];
  int ntN = N >> 6;
  int rem = bx - PAIR_START[p];
  int b = rem & 3; rem >>= 2;
  int nt = rem % ntN, mt = rem / ntN;
  int m0 = mt*64, n0 = nt*64;
  const unsigned short* FB = (const unsigned short*)(ws + OFF_FB3);
  const unsigned short* Ap = FB + (size_t)((si==0?0: si==1?256:1280) + b*M + m0)*256;
  const unsigned short* Bp = FB + (size_t)(5376 + (ti==0?0: ti==1?256:1280) + b*N + n0)*256;
  const int t = threadIdx.x, l = t&63, w = t>>6, wm = w&1, wn = w>>1;
  const int mrow = wm*32 + (l&15), ncol = wn*32 + (l&15);
  f32x4 acc[2][2];
  #pragma unroll
  for (int i=0;i<2;i++)
    #pragma unroll
    for (int j=0;j<2;j++) acc[i][j] = (f32x4){0.f,0.f,0.f,0.f};
  #pragma unroll
  for (int ksp=0; ksp<8; ++ksp){
    const int ko = ksp*32 + ((l>>4)&3)*8;
    short8v a0 = *(const short8v*)(Ap + (size_t) mrow     *256 + ko);
    short8v a1 = *(const short8v*)(Ap + (size_t)(mrow+16) *256 + ko);
    short8v b0 = *(const short8v*)(Bp + (size_t) ncol     *256 + ko);
    short8v b1 = *(const short8v*)(Bp + (size_t)(ncol+16) *256 + ko);
    acc[0][0] = __builtin_amdgcn_mfma_f32_16x16x32_bf16(a0, b0, acc[0][0], 0,0,0);
    acc[1][0] = __builtin_amdgcn_mfma_f32_16x16x32_bf16(a1, b0, acc[1][0], 0,0,0);
    acc[0][1] = __builtin_amdgcn_mfma_f32_16x16x32_bf16(a0, b1, acc[0][1], 0,0,0);
    acc[1][1] = __builtin_amdgcn_mfma_f32_16x16x32_bf16(a1, b1, acc[1][1], 0,0,0);
  }
  const float* iS = ws + OFF_INVS + (si==0?0: si==1?256:1280) + (size_t)b*M;
  const float* iT = ws + OFF_INVT + (ti==0?0: ti==1?256:1280) + (size_t)b*N;
  float* C = ws + PAIR_OFF[p] + (size_t)b*M*N;
  const int r0 = (l>>4)*4, cl = l&15;
  #pragma unroll
  for (int mf=0; mf<2; ++mf)
    #pragma unroll
    for (int nf=0; nf<2; ++nf)
      #pragma unroll
      for (int i=0;i<4;++i){
        int m = m0 + wm*32 + mf*16 + r0 + i;
        int n = n0 + wn*32 + nf*16 + cl;
        C[(size_t)m*N + n] = acc[mf][nf][i]*iS[m]*iT[n];
      }
}

// ---------------------------------------------------------------------------
DEVFN void cw_coord(int i, int n, int OH, int& i0, int& i1, float& f){
  float c = (float)(i*(n-1))/(float)(OH-1);
  int a = (int)c; if (a > n-1) a = n-1;
  i0 = a; i1 = (a+1 < n) ? a+1 : n-1; f = c - (float)a;
}

// 6) interp_pairs v2: block = (p,b,oy,ox); stage 4 corner (y,x) planes in LDS
__global__ __launch_bounds__(256) void k_interp_pairs(float* __restrict__ ws){
  int bx = blockIdx.x;
  int p = bx >> 10;
  int bl = bx & 1023;                    // [b:2][oy:4][ox:4]
  int b = bl >> 8, oy = (bl >> 4) & 15, ox = bl & 15;
  int si = p/3, ti = p%3;
  int h1 = SSARR[si], t1 = SSARR[ti], t12 = t1*t1;
  int y0,y1,x0,x1; float fy,fx;
  cw_coord(oy,h1,16,y0,y1,fy); cw_coord(ox,h1,16,x0,x1,fx);
  const float* in = ws + PAIR_OFF[p] + (size_t)b*h1*h1*t12;
  __shared__ float sPl[4][1024];
  const int t = threadIdx.x;
  {
    const float* pl0 = in + (size_t)(y0*h1+x0)*t12;
    const float* pl1 = in + (size_t)(y0*h1+x1)*t12;
    const float* pl2 = in + (size_t)(y1*h1+x0)*t12;
    const float* pl3 = in + (size_t)(y1*h1+x1)*t12;
    for (int i=t; i<t12; i+=256){
      sPl[0][i] = pl0[i]; sPl[1][i] = pl1[i];
      sPl[2][i] = pl2[i]; sPl[3][i] = pl3[i];
    }
  }
  __syncthreads();
  int px = t & 15, py = t >> 4;
  int u0,u1,v0,v1; float fu,fv;
  cw_coord(py,t1,16,u0,u1,fu); cw_coord(px,t1,16,v0,v1,fv);
  float wY[2]={1.f-fy,fy}, wX[2]={1.f-fx,fx};
  float wU[2]={1.f-fu,fu}, wV[2]={1.f-fv,fv};
  int us[2]={u0,u1}, vs[2]={v0,v1};
  float s = 0.f;
  #pragma unroll
  for (int qa=0; qa<2; qa++)
    #pragma unroll
    for (int qc=0; qc<2; qc++){
      float wyx = wY[qa]*wX[qc];
      const float* base = sPl[qa*2+qc];
      #pragma unroll
      for (int qu=0; qu<2; qu++)
        #pragma unroll
        for (int qv=0; qv<2; qv++)
          s += wyx*wU[qu]*wV[qv]*base[us[qu]*t1 + vs[qv]];
    }
  ws[OFF_CORR6 + ((size_t)b*9 + p)*65536 + ((size_t)(oy*16+ox)<<8) + t] = fmaxf(s, 0.f);
}

// ---------------------------------------------------------------------------
// 6b) k_cl v2: coalesced transpose via LDS (R14)
__global__ __launch_bounds__(256) void k_cl(float* __restrict__ ws){
  int bx = blockIdx.x;                      // 1024 = b*256 + yx
  int b = bx >> 8, yx = bx & 255;
  const int t = threadIdx.x;
  __shared__ __align__(16) unsigned short tile[10080];   // [yp20][xp21][pr24]
  for (int i=t; i<1260; i+=256)
    *reinterpret_cast<f32x4*>((float*)&tile[i*8]) = (f32x4){0.f,0.f,0.f,0.f};
  __syncthreads();
  const float* c6 = ws + OFF_CORR6 + ((size_t)b*9 << 16) + ((size_t)yx << 8);
  const int qy = t >> 4, qx = t & 15;
  const int wo = ((2+qy)*21 + 2+qx)*24;
  #pragma unroll
  for (int pr=0; pr<9; ++pr)
    tile[wo + pr] = f2bf(c6[((size_t)pr << 16) + t]);
  __syncthreads();
  unsigned short* o = (unsigned short*)(ws + OFF_CL) + (size_t)bx*10080;
  for (int i=t; i<1260; i+=256)
    *reinterpret_cast<f32x4*>((float*)&o[i*8]) =
      *reinterpret_cast<const f32x4*>((const float*)&tile[i*8]);
}

// ---------------------------------------------------------------------------
// 7) chm6d v7: bf16 MFMA implicit GEMM + fused sigmoid/max epilogue (R11)
__global__ __launch_bounds__(256) void k_chm6d(float* __restrict__ ws){
  int id = (blockIdx.x & 7)*128 + (blockIdx.x >> 3);   // XCD swizzle, bijective
  const int b = id >> 8, sy = (id >> 4) & 15, sx = id & 15;
  const int t = threadIdx.x, l = t & 63, w = t >> 6;
  const int x = l & 15, h = (l >> 4) & 1, e2 = (l >> 4) >> 1;
  const unsigned short* CLu = (const unsigned short*)(ws + OFF_CL);
  const unsigned short* WAu = (const unsigned short*)(ws + OFF_WA);
  __shared__ __align__(16) unsigned short tile[2][10080];   // 40,320 B

  f32x4 acc[4];
  #pragma unroll
  for (int i=0;i<4;i++) acc[i] = (f32x4){0.f,0.f,0.f,0.f};

  auto STAGE = [&](int buf, int YX){
    const unsigned short* src = CLu + (size_t)(b*256 + YX)*10080;
    #pragma unroll
    for (int j=0;j<5;++j){
      int ch = t + j*256;
      if (ch < 1260) gl_lds16(src + (size_t)ch*8, &tile[buf][ch*8]);
    }
  };

  const int xb0 = (x + e2)*24 + 8*h;

  int i0 = 0;
  for (; i0 < 25; ++i0){
    int Y = sy + i0/5 - 2, X = sx + i0%5 - 2;
    if (Y>=0 && Y<=15 && X>=0 && X<=15) break;
  }
  {
    int Y = sy + i0/5 - 2, X = sx + i0%5 - 2;
    STAGE(0, Y*16 + X);
  }
  __syncthreads();
  int buf = 0, i = i0;
  #pragma unroll 1
  while (i < 25){
    int nx = i + 1;
    for (; nx < 25; ++nx){
      int Y = sy + nx/5 - 2, X = sx + nx%5 - 2;
      if (Y>=0 && Y<=15 && X>=0 && X<=15) break;
    }
    if (nx < 25){
      int Y = sy + nx/5 - 2, X = sx + nx%5 - 2;
      STAGE(buf^1, Y*16 + X);
    }
    {
      const unsigned short* wa = WAu + (size_t)i*5*3*512;   // [d][kc][lane][8]
      short8v afr[5][3];
      #pragma unroll
      for (int d=0; d<5; ++d)
        #pragma unroll
        for (int kc=0; kc<3; ++kc)
          afr[d][kc] = *(const short8v*)&wa[((d*3 + kc)*64 + l)*8];
      const unsigned short* tb = &tile[buf][0];
      #pragma unroll
      for (int rl=0; rl<8; ++rl){
        const int row = (w*4 + rl)*504;
        short8v bf0 = *(const short8v*)&tb[row + xb0];
        short8v bf1 = *(const short8v*)&tb[row + xb0 + 48];
        short8v bf2 = *(const short8v*)&tb[row + xb0 + 96];
        #pragma unroll
        for (int y=0; y<4; ++y){
          if (y <= rl && rl - y <= 4){
            const int d = rl - y;
            acc[y] = __builtin_amdgcn_mfma_f32_16x16x32_bf16(afr[d][0], bf0, acc[y], 0,0,0);
            acc[y] = __builtin_amdgcn_mfma_f32_16x16x32_bf16(afr[d][1], bf1, acc[y], 0,0,0);
            acc[y] = __builtin_amdgcn_mfma_f32_16x16x32_bf16(afr[d][2], bf2, acc[y], 0,0,0);
          }
        }
      }
    }
    __syncthreads();
    buf ^= 1; i = nx;
  }

  const int g = l >> 4;
  float* maxed = ws + OFF_MAXED + (size_t)b*65536 + (size_t)(sy*16+sx)*256;
  #pragma unroll
  for (int y=0; y<4; ++y){
    float lm;
    if (g < 2)      lm = fmaxf(fmaxf(acc[y][0], acc[y][1]), fmaxf(acc[y][2], acc[y][3]));
    else if (g==2)  lm = acc[y][0];
    else            lm = -1e30f;
    lm = fmaxf(lm, __shfl_xor(lm, 16));
    lm = fmaxf(lm, __shfl_xor(lm, 32));
    if (l < 16)
      maxed[(w*4 + y)*16 + x] = 1.f/(1.f + expf(-lm));
  }
}

// ---------------------------------------------------------------------------
// 8) interpolate4d 16^4 -> 32^4
__global__ void k_interp32(float* __restrict__ ws){
  int id = blockIdx.x*256 + threadIdx.x;
  int px = id & 31, py = (id>>5)&31, ox = (id>>10)&31, oy = (id>>15)&31, b = id>>20;
  int y0,y1,x0,x1,u0,u1,v0,v1; float fy,fx,fu,fv;
  cw_coord(oy,16,32,y0,y1,fy); cw_coord(ox,16,32,x0,x1,fx);
  cw_coord(py,16,32,u0,u1,fu); cw_coord(px,16,32,v0,v1,fv);
  const float* in = ws + OFF_MAXED + (size_t)b*65536;
  int ys[2]={y0,y1}, xs[2]={x0,x1}, us[2]={u0,u1}, vs[2]={v0,v1};
  float wy[2]={1.f-fy,fy}, wx[2]={1.f-fx,fx}, wu[2]={1.f-fu,fu}, wv[2]={1.f-fv,fv};
  float s = 0.f;
  #pragma unroll
  for (int ia=0; ia<2; ia++)
    #pragma unroll
    for (int ic=0; ic<2; ic++){
      float wyx = wy[ia]*wx[ic];
      const float* base = in + ((size_t)ys[ia]*16 + xs[ic])*256;
      #pragma unroll
      for (int id_=0; id_<2; id_++)
        #pragma unroll
        for (int ie=0; ie<2; ie++)
          s += wyx*wu[id_]*wv[ie]*base[(size_t)us[id_]*16 + vs[ie]];
    }
  ws[OFF_INT32 + id] = s;
}

// ---------------------------------------------------------------------------
// 9) fast4d v7: bf16 MFMA implicit GEMM (R18)
__global__ __launch_bounds__(256) void k_fast4d(float* __restrict__ ws,
                                                const float* __restrict__ b4,
                                                float* __restrict__ out){
  int id = (blockIdx.x & 7)*128 + (blockIdx.x >> 3);   // bijective 1024
  const int b = id >> 8, rem = id & 255;
  const int syb = rem >> 5, sxb = (rem >> 2) & 7, yh = rem & 3;
  const int t = threadIdx.x, l = t & 63, w = t >> 6;
  __shared__ __align__(16) unsigned short T[27648];    // 55,296 B
  __shared__ float red[4][16];
  for (int i=t; i<3456; i+=256)
    *reinterpret_cast<f32x4*>((float*)&T[i*8]) = (f32x4){0.f,0.f,0.f,0.f};
  __syncthreads();
  const float* I = ws + OFF_INT32 + (size_t)b*1048576;
  #pragma unroll 4
  for (int j=0; j<48; ++j){
    int idx2 = j*256 + t;
    int xo = idx2 & 15, pl = (idx2>>4) & 63, ry = idx2 >> 10;
    int pya = syb*4 + (pl>>3) - 2;
    int pxa = sxb*4 + (pl&7) - 2;
    int rya = yh*8 + ry - 2;
    if (pya>=0 && pya<32 && pxa>=0 && pxa<32 && rya>=0 && rya<32){
      float2 v = *reinterpret_cast<const float2*>(
          I + (size_t)(pya*32+pxa)*1024 + rya*32 + xo*2);
      int base = (ry*36 + xo*2 + 2)*64 + pl;
      T[base]      = f2bf(v.x);
      T[base + 64] = f2bf(v.y);
    }
  }
  __syncthreads();
  const unsigned short* WA4 = (const unsigned short*)(ws + OFF_WA4);
  f32x4 acc[2][2];
  #pragma unroll
  for (int i=0;i<2;i++)
    #pragma unroll
    for (int j=0;j<2;j++) acc[i][j] = (f32x4){0.f,0.f,0.f,0.f};
  const unsigned short* Tl = T + (l&15)*64 + (l>>4)*8 + w*2*2304;
  #pragma unroll 1
  for (int d=0; d<5; ++d){
    short8v afr[10];
    #pragma unroll
    for (int kc=0; kc<10; ++kc)
      afr[kc] = *(const short8v*)&WA4[((size_t)(d*10 + kc)*64 + l)*8];
    #pragma unroll
    for (int y2=0; y2<2; ++y2){
      const unsigned short* Tr = Tl + (y2 + d)*2304;
      #pragma unroll
      for (int xg=0; xg<2; ++xg){
        const unsigned short* Tx = Tr + xg*1024;
        #pragma unroll
        for (int kc=0; kc<10; ++kc){
          short8v bf = *(const short8v*)&Tx[(kc>>1)*64 + (kc&1)*32];
          acc[y2][xg] = __builtin_amdgcn_mfma_f32_16x16x32_bf16(afr[kc], bf, acc[y2][xg], 0,0,0);
        }
      }
    }
  }
  const float bias = b4[0];
  float rm[4] = {-1e30f,-1e30f,-1e30f,-1e30f};
  #pragma unroll
  for (int y2=0; y2<2; ++y2)
    #pragma unroll
    for (int xg=0; xg<2; ++xg)
      #pragma unroll
      for (int i=0; i<4; ++i){
        int so = (l>>4)*4 + i;
        float xv = acc[y2][xg][i] + bias;
        float sp = fmaxf(xv,0.f) + log1pf(expf(-fabsf(xv)));
        int row = (syb*4 + (so>>2))*32 + sxb*4 + (so&3);
        int col = (yh*8 + w*2 + y2)*32 + xg*16 + (l&15);
        out[((size_t)b*1024 + row)*1024 + col] = sp;
        rm[i] = fmaxf(rm[i], sp);
      }
  #pragma unroll
  for (int m=1; m<16; m<<=1)
    #pragma unroll
    for (int i=0;i<4;++i) rm[i] = fmaxf(rm[i], __shfl_xor(rm[i], m));
  if ((l & 15) == 0){
    #pragma unroll
    for (int i=0;i<4;++i) red[w][(l>>4)*4 + i] = rm[i];
  }
  __syncthreads();
  if (t < 16){
    float m = fmaxf(fmaxf(red[0][t], red[1][t]), fmaxf(red[2][t], red[3][t]));
    int row = (syb*4 + (t>>2))*32 + sxb*4 + (t&3);
    ws[OFF_SMAXP + (size_t)yh*4096 + (size_t)b*1024 + row] = m;
  }
}

// ---------------------------------------------------------------------------
// 10-12) mutual_nn_filter
__global__ void k_colmax_p(const float* __restrict__ cm, float* __restrict__ ws){
  int b = blockIdx.x >> 7, rg = (blockIdx.x >> 2) & 31, cg = blockIdx.x & 3;
  int c = cg*256 + threadIdx.x;
  const float* base = cm + (size_t)b*1048576 + (size_t)rg*32768 + c;
  float m = -1e30f;
  #pragma unroll 4
  for (int r=0; r<32; r++) m = fmaxf(m, base[(size_t)r*1024]);
  ws[OFF_CMAXP + (size_t)(b*32+rg)*1024 + c] = m;
}

__global__ void k_colmax_r(float* __restrict__ ws){
  int id = blockIdx.x*256 + threadIdx.x;         // 4096
  int b = id >> 10, c = id & 1023;
  float m = -1e30f;
  #pragma unroll
  for (int rg=0; rg<32; rg++)
    m = fmaxf(m, ws[OFF_CMAXP + (size_t)(b*32+rg)*1024 + c]);
  ws[OFF_TMAX + id] = m;
}

__global__ void k_mutual(float* __restrict__ cm, const float* __restrict__ ws){
  int id = blockIdx.x*256 + threadIdx.x;
  int b = id >> 20, r = (id>>10)&1023, c = id&1023;
  float v  = cm[id];
  size_t si = (size_t)(b<<10) + r;
  float sm = fmaxf(fmaxf(ws[OFF_SMAXP + si],        ws[OFF_SMAXP + 4096 + si]),
                   fmaxf(ws[OFF_SMAXP + 8192 + si], ws[OFF_SMAXP + 12288 + si]));
  float tm = ws[OFF_TMAX + (b<<10) + c];
  sm = (sm==0.f) ? 1e-30f : sm;
  tm = (tm==0.f) ? 1e-30f : tm;
  cm[id] = v * (v/sm) * (v/tm);
}

// ---------------------------------------------------------------------------
extern "C" void kernel_launch(void* const* d_in, const int* in_sizes, int n_in,
                              void* d_out, int out_size, void* d_ws, size_t ws_size,
                              hipStream_t stream){
  const float* src = (const float*)d_in[0];
  const float* trg = (const float*)d_in[1];
  const float* w0  = (const float*)d_in[2];
  const float* w1  = (const float*)d_in[3];
  const float* w2  = (const float*)d_in[4];
  const float* k6  = (const float*)d_in[5];
  const float* k4  = (const float*)d_in[6];
  const float* b4  = (const float*)d_in[7];
  float* ws  = (float*)d_ws;    // needs WS_FLOATS*4 = ~78.1 MB
  float* out = (float*)d_out;
  (void)in_sizes; (void)n_in; (void)out_size; (void)ws_size;

  k_wpack       <<<768,   256, 0, stream>>>(w0, w1, w2, ws);
  k_wa          <<<94,    256, 0, stream>>>(k6, ws);
  k_wa4         <<<13,    256, 0, stream>>>(k4, ws);
  k_inpack      <<<512,   256, 0, stream>>>(src, trg, ws);
  k_conv_mfma   <<<672,   256, 0, stream>>>(ws);
  k_fbpack      <<<168,   256, 0, stream>>>(ws);
  k_invnorm     <<<672,   256, 0, stream>>>(ws);
  k_corr        <<<1764,  256, 0, stream>>>(ws);
  k_interp_pairs<<<9216,  256, 0, stream>>>(ws);
  k_cl          <<<1024,  256, 0, stream>>>(ws);
  k_chm6d       <<<1024,  256, 0, stream>>>(ws);
  k_interp32    <<<16384, 256, 0, stream>>>(ws);
  k_fast4d      <<<1024,  256, 0, stream>>>(ws, b4, out);
  k_colmax_p    <<<512,   256, 0, stream>>>(out, ws);
  k_colmax_r    <<<16,    256, 0, stream>>>(ws);
  k_mutual      <<<16384, 256, 0, stream>>>(out, ws);
}